// Round 2
// baseline (945.156 us; speedup 1.0000x reference)
//
#include <hip/hip_runtime.h>

typedef unsigned short bfu;                                     // bf16 storage
typedef __attribute__((ext_vector_type(8))) __bf16 bf16x8;      // MFMA A/B frag
typedef __attribute__((ext_vector_type(4))) float f32x4;        // MFMA C/D frag

__device__ __forceinline__ float bf2f(bfu u) {
    unsigned int x = ((unsigned int)u) << 16;
    return __builtin_bit_cast(float, x);
}
__device__ __forceinline__ bfu f2bf(float f) {  // round-nearest-even
    unsigned int u = __builtin_bit_cast(unsigned int, f);
    unsigned int r = (u + 0x7fffu + ((u >> 16) & 1u)) >> 16;
    return (bfu)r;
}
__device__ __forceinline__ float sigm(float x) { return 1.0f / (1.0f + __expf(-x)); }
__device__ __forceinline__ float gelu_f(float x) {
    return 0.5f * x * (1.0f + erff(x * 0.70710678118654752f));  // exact-erf GELU
}

// async global->LDS, 16B per lane; LDS dest = wave-uniform base + lane*16.
// NOTE: global src addr is per-lane arbitrary -> we swizzle the SOURCE chunk.
__device__ __forceinline__ void async16(const void* g, void* l) {
    __builtin_amdgcn_global_load_lds((const __attribute__((address_space(1))) void*)g,
                                     (__attribute__((address_space(3))) void*)l, 16, 0, 0);
}

// ---------------------------------------------------------------- transpose
// fp32 [K][N] -> bf16 [N][K]; all K,N are multiples of 64. 9 matrices batched.
struct TDesc { const float* src; bfu* dst; int K, N, blk0; };
struct TPack { TDesc d[9]; };

__global__ __launch_bounds__(256) void transpose_k(TPack p) {
    const int bid = blockIdx.x;
    int j = 0;
#pragma unroll
    for (int i = 1; i < 9; ++i)
        if (bid >= p.d[i].blk0) j = i;
    const TDesc d = p.d[j];
    const int local = bid - d.blk0;
    const int tkn = d.K >> 6;
    const int tk = local % tkn, tn = local / tkn;
    const int k0 = tk * 64, n0 = tn * 64;
    __shared__ float tile[64][65];  // +1 pad: conflict-free transpose read
    const int tx = threadIdx.x & 63, ty = threadIdx.x >> 6;
#pragma unroll
    for (int i = 0; i < 16; ++i) {
        const int r = ty * 16 + i;
        tile[r][tx] = d.src[(size_t)(k0 + r) * d.N + n0 + tx];
    }
    __syncthreads();
#pragma unroll
    for (int i = 0; i < 16; ++i) {
        const int n = ty * 16 + i;
        d.dst[(size_t)(n0 + n) * d.K + k0 + tx] = f2bf(tile[tx][n]);
    }
}

// ------------------------------------------------------- geometric + cast
// one wave per row of 768 fp32: geometric quality (out rows), bf16 cast,
// and (cq+dq)/3 partial of the information head (phase 1 only).
__global__ __launch_bounds__(256)
void geomcast_k(const float* F0, const float* F1, bfu* D0, bfu* D1,
                float* g0, float* g1, float* p0, float* p1) {
    const int z = blockIdx.y;
    const float* F = z ? F1 : F0;
    bfu* D = z ? D1 : D0;
    float* gout = z ? g1 : g0;
    float* part = z ? p1 : p0;
    const int wave = threadIdx.x >> 6, lane = threadIdx.x & 63;
    const int row = blockIdx.x * 4 + wave;
    const float* fr = F + (size_t)row * 768;
    bfu* dr = D + (size_t)row * 768;
    float sum = 0.f, ss = 0.f, cnt = 0.f;
#pragma unroll
    for (int i = 0; i < 3; ++i) {
        const float4 v = *(const float4*)(fr + i * 256 + lane * 4);
        sum += v.x + v.y + v.z + v.w;
        ss += v.x * v.x + v.y * v.y + v.z * v.z + v.w * v.w;
        cnt += ((fabsf(v.x) > 0.01f) ? 1.f : 0.f) + ((fabsf(v.y) > 0.01f) ? 1.f : 0.f) +
               ((fabsf(v.z) > 0.01f) ? 1.f : 0.f) + ((fabsf(v.w) > 0.01f) ? 1.f : 0.f);
        ushort4 b;
        b.x = f2bf(v.x); b.y = f2bf(v.y); b.z = f2bf(v.z); b.w = f2bf(v.w);
        *(ushort4*)(dr + i * 256 + lane * 4) = b;
    }
#pragma unroll
    for (int off = 32; off; off >>= 1) {
        sum += __shfl_xor(sum, off);
        ss  += __shfl_xor(ss, off);
        cnt += __shfl_xor(cnt, off);
    }
    if (lane == 0) {
        const float n = sqrtf(ss);
        const float nq = sigm((n - 1.f) * 2.f);
        const float sp = cnt * (1.f / 768.f);
        float var = (ss - sum * sum * (1.f / 768.f)) * (1.f / 767.f);
        var = fmaxf(var, 0.f);
        const float sq = sigm(sqrtf(var) * 10.f - 1.f);  // torch.std ddof=1
        gout[row] = (nq + sp + sq) * (1.f / 3.f);
        if (part) {
            const float cq = (n > 0.01f) ? (1.f / 768.f) : 0.f;
            const float nc = fmaxf(n, 1e-12f);
            const float dq = sigm(ss / (nc * nc) - 0.5f);
            part[row] = (cq + dq) * (1.f / 3.f);
        }
    }
}

// ------------------------------------------------------------------- GEMM
// C[M,N] = act(A[M,K] @ W[K,N] + bias), W pre-transposed bf16 [N][K].
// cols >= Ksplit of A come from A2 (for the 2H concat heads).
// blockIdx.x = N-tile (fastest: keeps small W L2-resident, streams A once).
// LDS XOR-swizzle: logical chunk q of row r lives at physical chunk q^(r&7);
// staging fetches global chunk s^(r&7) into physical slot s (global addr is
// per-lane, LDS dest stays contiguous as global_load_lds requires). Row-lanes
// then spread across all 32 banks (2-way alias only, free per m136).
template <int BN>
__global__ __launch_bounds__(256)
void gemm_k(const bfu* __restrict__ A, const bfu* __restrict__ A2,
            const bfu* __restrict__ Wt, const float* __restrict__ bias,
            bfu* Cb, float* Cf, int N, int K, int Ksplit, int lda, int ldc, int act) {
    constexpr int BM = 128, BK = 64;
    constexpr int MT = (BN == 128) ? 4 : 2;
    constexpr int NT = 4;
    __shared__ bfu As[BM * BK];
    __shared__ bfu Ws[BN * BK];
    const int t = threadIdx.x;
    const int wave = t >> 6, lane = t & 63;
    const int row_l = lane & 15, kq = lane >> 4;
    const int n0 = blockIdx.x * BN;
    const int m0 = blockIdx.y * BM;
    const int wm = (BN == 128) ? (wave >> 1) : wave;
    const int wn = (BN == 128) ? (wave & 1) : 0;
    const int wrow0 = wm * (MT * 16);
    const int wcol0 = wn * 64;

    f32x4 acc[MT][NT] = {};

    const int nkt = K / BK;
    for (int kt = 0; kt < nkt; ++kt) {
        const int k0 = kt * BK;
        const bfu* Ab;
        int kc;
        if (k0 < Ksplit) { Ab = A; kc = k0; }
        else             { Ab = A2; kc = k0 - Ksplit; }
#pragma unroll
        for (int i = 0; i < 4; ++i) {               // A tile: 128x64
            const int c = i * 256 + t;
            const int r = c >> 3, s = c & 7;
            const int cc = (s ^ (r & 7)) << 3;      // swizzled source chunk
            async16(Ab + (size_t)(m0 + r) * lda + kc + cc, As + ((i * 256 + wave * 64) << 3));
        }
#pragma unroll
        for (int i = 0; i < BN / 32; ++i) {         // W tile: BNx64
            const int c = i * 256 + t;
            const int r = c >> 3, s = c & 7;
            const int cc = (s ^ (r & 7)) << 3;
            async16(Wt + (size_t)(n0 + r) * K + k0 + cc, Ws + ((i * 256 + wave * 64) << 3));
        }
        __syncthreads();
#pragma unroll
        for (int ks = 0; ks < 2; ++ks) {
            bf16x8 af[MT], bfr[NT];
#pragma unroll
            for (int mi = 0; mi < MT; ++mi) {
                const int rA = wrow0 + mi * 16 + row_l;
                af[mi] = *(const bf16x8*)(As + rA * BK + (((ks * 4 + kq) ^ (rA & 7)) << 3));
            }
#pragma unroll
            for (int ni = 0; ni < NT; ++ni) {
                const int rB = wcol0 + ni * 16 + row_l;
                bfr[ni] = *(const bf16x8*)(Ws + rB * BK + (((ks * 4 + kq) ^ (rB & 7)) << 3));
            }
#pragma unroll
            for (int mi = 0; mi < MT; ++mi)
#pragma unroll
                for (int ni = 0; ni < NT; ++ni)
                    acc[mi][ni] = __builtin_amdgcn_mfma_f32_16x16x32_bf16(af[mi], bfr[ni], acc[mi][ni], 0, 0, 0);
        }
        __syncthreads();
    }

    // epilogue: C/D layout col=lane&15, row=quad*4+reg (verified m89/m91)
#pragma unroll
    for (int ni = 0; ni < NT; ++ni) {
        const int col = n0 + wcol0 + ni * 16 + row_l;
        const float bv = bias[col];
#pragma unroll
        for (int mi = 0; mi < MT; ++mi) {
#pragma unroll
            for (int r = 0; r < 4; ++r) {
                const int row = m0 + wrow0 + mi * 16 + kq * 4 + r;
                float v = acc[mi][ni][r] + bv;
                if (act) v = gelu_f(v);
                const size_t idx = (size_t)row * ldc + col;
                if (Cb) Cb[idx] = f2bf(v);
                else    Cf[idx] = v;
            }
        }
    }
}

// ----------------------------------------------------------- entropy head
// wave per row: 64 fp32 logits -> round(sig*10) -> histogram entropy.
// E is [2B x 64]: rows < B -> out row 4 (img), else out row 5 (txt).
__global__ __launch_bounds__(256)
void entropy_k(const float* E, const float* part, float* out, int B) {
    const int wave = threadIdx.x >> 6, lane = threadIdx.x & 63;
    const int row = blockIdx.x * 4 + wave;
    const float e = E[(size_t)row * 64 + lane];
    const int d = (int)rintf(sigm(e) * 10.f);  // np.round = half-to-even = rintf
    float ent = 0.f;
#pragma unroll
    for (int b = 0; b <= 10; ++b) {
        const unsigned long long m = __ballot(d == b);
        const int c = __popcll(m);
        if (c > 0) {
            const float p = (float)c * (1.f / 64.f);
            ent -= p * __logf(p + 1e-8f);
        }
    }
    if (lane == 0) {
        const int orow = (row < B) ? 4 : 5;
        const int rl = (row < B) ? row : row - B;
        out[(size_t)orow * B + rl] = part[row] + sigm(ent - 2.f) * (1.f / 3.f);
    }
}

// -------------------------------------------------- final N->1 dot+sigmoid
// segmented: up to 2 segments per launch; seg rows are multiples of B; the
// out row is o0 for local<B else o1.
struct RSeg { const bfu* A; const float* w; const float* bs; int lda, N, rows, o0, o1; };
struct RPack { RSeg s[2]; };

__global__ __launch_bounds__(256)
void rowdot_k(RPack p, float* out, int B) {
    const int wave = threadIdx.x >> 6, lane = threadIdx.x & 63;
    const int gr = blockIdx.x * 4 + wave;
    RSeg sg;
    int local;
    if (gr < p.s[0].rows) { sg = p.s[0]; local = gr; }
    else                  { sg = p.s[1]; local = gr - p.s[0].rows; }
    const bfu* hr = sg.A + (size_t)local * sg.lda;
    float s = 0.f;
    for (int k = lane; k < sg.N; k += 64) s += bf2f(hr[k]) * sg.w[k];
#pragma unroll
    for (int off = 32; off; off >>= 1) s += __shfl_xor(s, off);
    if (lane == 0) {
        const int orow = (local < B) ? sg.o0 : sg.o1;
        const int rl = (local < B) ? local : local - B;
        out[(size_t)orow * B + rl] = sigm(s + sg.bs[0]);
    }
}

__global__ __launch_bounds__(256) void finalize_k(float* out, int B) {
    const int i = blockIdx.x * 256 + threadIdx.x;
    if (i < B) {
        const float v = out[0 * B + i] + out[1 * B + i] + out[4 * B + i] + out[5 * B + i] +
                        out[7 * B + i] + 0.5f * (out[8 * B + i] + out[9 * B + i]);
        out[17 * B + i] = v * (1.f / 6.f);
    }
}

extern "C" void kernel_launch(void* const* d_in, const int* in_sizes, int n_in,
                              void* d_out, int out_size, void* d_ws, size_t ws_size,
                              hipStream_t stream) {
    const int B = in_sizes[4];  // 16384
    const int B2 = 2 * B;
    float* out = (float*)d_out;
    const float* img  = (const float*)d_in[0];
    const float* txt  = (const float*)d_in[1];
    const float* eimg = (const float*)d_in[2];
    const float* etxt = (const float*)d_in[3];
    const float* info_w1 = (const float*)d_in[5];  const float* info_b1 = (const float*)d_in[6];
    const float* info_w2 = (const float*)d_in[7];  const float* info_b2 = (const float*)d_in[8];
    const float* imp_w1  = (const float*)d_in[9];  const float* imp_b1  = (const float*)d_in[10];
    const float* imp_w2  = (const float*)d_in[11]; const float* imp_b2  = (const float*)d_in[12];
    const float* disc_w1 = (const float*)d_in[13]; const float* disc_b1 = (const float*)d_in[14];
    const float* disc_w2 = (const float*)d_in[15]; const float* disc_b2 = (const float*)d_in[16];
    const float* disc_w3 = (const float*)d_in[17]; const float* disc_b3 = (const float*)d_in[18];
    const float* cons_w1 = (const float*)d_in[19]; const float* cons_b1 = (const float*)d_in[20];
    const float* cons_w2 = (const float*)d_in[21]; const float* cons_b2 = (const float*)d_in[22];
    const float* cons_w3 = (const float*)d_in[23]; const float* cons_b3 = (const float*)d_in[24];
    const float* diff_w1 = (const float*)d_in[25]; const float* diff_b1 = (const float*)d_in[26];
    const float* diff_w2 = (const float*)d_in[27]; const float* diff_b2 = (const float*)d_in[28];
    const float* diff_w3 = (const float*)d_in[29]; const float* diff_b3 = (const float*)d_in[30];

    char* wsp = (char*)d_ws;
    size_t off = 0;
    auto alloc = [&](size_t bytes) -> void* {
        void* p = wsp + off;
        off += (bytes + 255) & ~(size_t)255;
        return p;
    };
    // persistent weights (bf16, transposed [N][K])
    bfu* info1t = (bfu*)alloc((size_t)256 * 768 * 2);
    bfu* info2t = (bfu*)alloc((size_t)64 * 256 * 2);
    bfu* imp1t  = (bfu*)alloc((size_t)384 * 768 * 2);
    bfu* disc1t = (bfu*)alloc((size_t)256 * 768 * 2);
    bfu* disc2t = (bfu*)alloc((size_t)64 * 256 * 2);
    bfu* cons1t = (bfu*)alloc((size_t)768 * 1536 * 2);
    bfu* cons2t = (bfu*)alloc((size_t)384 * 768 * 2);
    bfu* diff1t = (bfu*)alloc((size_t)768 * 1536 * 2);
    bfu* diff2t = (bfu*)alloc((size_t)384 * 768 * 2);
    float* part = (float*)alloc((size_t)B2 * 4);
    // reusable regions (peak ws ~116.6 MB, under round-1-proven 133 MB)
    bfu* fA01 = (bfu*)alloc((size_t)B2 * 768 * 2);                       // R1 50.3 MB
    char* R2 = (char*)alloc((size_t)B2 * 384 * 2 + (size_t)B2 * 256 * 2); // 41.9 MB
    char* R3 = (char*)alloc((size_t)B2 * 64 * 2 + (size_t)B * 384 * 2);   // 16.8 MB
    bfu* Hi  = (bfu*)R2;                    // [2B x 256] info l1
    bfu* Hm  = (bfu*)R2;                    // [2B x 384] imp l1
    bfu* Hd  = (bfu*)(R2 + (size_t)B2 * 384 * 2);  // [2B x 256] disc l1
    bfu* Hc  = (bfu*)R2;                    // [B x 768] concat l1 (cons/diff)
    float* E  = (float*)R3;                 // [2B x 64] fp32 info l2
    bfu* H2d = (bfu*)R3;                    // [2B x 64] disc l2
    bfu* H2a = (bfu*)(R3 + (size_t)B2 * 64 * 2);   // [B x 384] cons/diff l2
    (void)ws_size; (void)n_in; (void)out_size;

    // ---- weight prep (every call: ws is re-poisoned) ----
    TPack tp;
    int blk = 0, ti = 0;
    auto setd = [&](const float* s, bfu* d, int K, int N) {
        tp.d[ti++] = {s, d, K, N, blk};
        blk += (K / 64) * (N / 64);
    };
    setd(info_w1, info1t, 768, 256);
    setd(info_w2, info2t, 256, 64);
    setd(imp_w1, imp1t, 768, 384);
    setd(disc_w1, disc1t, 768, 256);
    setd(disc_w2, disc2t, 256, 64);
    setd(cons_w1, cons1t, 1536, 768);
    setd(cons_w2, cons2t, 768, 384);
    setd(diff_w1, diff1t, 1536, 768);
    setd(diff_w2, diff2t, 768, 384);
    transpose_k<<<dim3(blk), 256, 0, stream>>>(tp);

    const int MY2 = B2 / 128, MY1 = B / 128;  // M-tiles

    auto phase = [&](const float* Fa, const float* Fb, int pb) {
        // geomcast: [Fa;Fb] -> fA01 bf16, geometric -> out rows, parts (phase A)
        geomcast_k<<<dim3(B / 4, 2), 256, 0, stream>>>(
            Fa, Fb, fA01, fA01 + (size_t)B * 768,
            out + (size_t)(pb ? 2 : 0) * B, out + (size_t)(pb ? 3 : 1) * B,
            pb ? nullptr : part, pb ? nullptr : part + B);
        if (!pb) {  // information head: only img/txt
            gemm_k<128><<<dim3(2, MY2), 256, 0, stream>>>(fA01, fA01, info1t, info_b1,
                                                          Hi, nullptr, 256, 768, 768, 768, 256, 1);
            gemm_k<64><<<dim3(1, MY2), 256, 0, stream>>>(Hi, Hi, info2t, info_b2,
                                                         nullptr, E, 64, 256, 256, 256, 64, 0);
            entropy_k<<<dim3(B2 / 4), 256, 0, stream>>>(E, part, out, B);
        }
        // importance l1 + discriminator l1/l2
        gemm_k<128><<<dim3(3, MY2), 256, 0, stream>>>(fA01, fA01, imp1t, imp_b1,
                                                      Hm, nullptr, 384, 768, 768, 768, 384, 1);
        gemm_k<128><<<dim3(2, MY2), 256, 0, stream>>>(fA01, fA01, disc1t, disc_b1,
                                                      Hd, nullptr, 256, 768, 768, 768, 256, 1);
        gemm_k<64><<<dim3(1, MY2), 256, 0, stream>>>(Hd, Hd, disc2t, disc_b2,
                                                     H2d, nullptr, 64, 256, 256, 256, 64, 1);
        {   // merged rowdot: imp (out 8,9 / 10,11) + disc (out 12,14 / 13,15)
            RPack rp;
            rp.s[0] = {Hm, imp_w2, imp_b2, 384, 384, B2, pb ? 10 : 8, pb ? 11 : 9};
            rp.s[1] = {H2d, disc_w3, disc_b3, 64, 64, B2, pb ? 13 : 12, pb ? 15 : 14};
            rowdot_k<<<dim3(B2 * 2 / 4), 256, 0, stream>>>(rp, out, B);
        }
        // consistency head on concat [Fa|Fb]
        gemm_k<128><<<dim3(6, MY1), 256, 0, stream>>>(fA01, fA01 + (size_t)B * 768, cons1t, cons_b1,
                                                      Hc, nullptr, 768, 1536, 768, 768, 768, 1);
        gemm_k<128><<<dim3(3, MY1), 256, 0, stream>>>(Hc, Hc, cons2t, cons_b2,
                                                      H2a, nullptr, 384, 768, 768, 768, 384, 1);
        {
            RPack rp;
            rp.s[0] = {H2a, cons_w3, cons_b3, 384, 384, B, pb ? 7 : 6, pb ? 7 : 6};
            rp.s[1] = rp.s[0];
            rowdot_k<<<dim3(B / 4), 256, 0, stream>>>(rp, out, B);
        }
        if (pb) {  // task-difficulty head (enhanced concat only)
            gemm_k<128><<<dim3(6, MY1), 256, 0, stream>>>(fA01, fA01 + (size_t)B * 768, diff1t, diff_b1,
                                                          Hc, nullptr, 768, 1536, 768, 768, 768, 1);
            gemm_k<128><<<dim3(3, MY1), 256, 0, stream>>>(Hc, Hc, diff2t, diff_b2,
                                                          H2a, nullptr, 384, 768, 768, 768, 384, 1);
            RPack rp;
            rp.s[0] = {H2a, diff_w3, diff_b3, 384, 384, B, 16, 16};
            rp.s[1] = rp.s[0];
            rowdot_k<<<dim3(B / 4), 256, 0, stream>>>(rp, out, B);
        }
    };

    phase(img, txt, 0);
    phase(eimg, etxt, 1);

    finalize_k<<<dim3((B + 255) / 256), 256, 0, stream>>>(out, B);
}

// Round 3
// 803.063 us; speedup vs baseline: 1.1769x; 1.1769x over previous
//
#include <hip/hip_runtime.h>

typedef unsigned short bfu;                                     // bf16 storage
typedef __attribute__((ext_vector_type(8))) __bf16 bf16x8;      // MFMA A/B frag
typedef __attribute__((ext_vector_type(4))) float f32x4;        // MFMA C/D frag

__device__ __forceinline__ float bf2f(bfu u) {
    unsigned int x = ((unsigned int)u) << 16;
    return __builtin_bit_cast(float, x);
}
__device__ __forceinline__ bfu f2bf(float f) {  // round-nearest-even
    unsigned int u = __builtin_bit_cast(unsigned int, f);
    unsigned int r = (u + 0x7fffu + ((u >> 16) & 1u)) >> 16;
    return (bfu)r;
}
__device__ __forceinline__ float sigm(float x) { return 1.0f / (1.0f + __expf(-x)); }
__device__ __forceinline__ float gelu_f(float x) {
    return 0.5f * x * (1.0f + erff(x * 0.70710678118654752f));  // exact-erf GELU
}

// async global->LDS, 16B/lane; LDS dest = wave-uniform base + lane*16.
__device__ __forceinline__ void async16(const void* g, void* l) {
    __builtin_amdgcn_global_load_lds((const __attribute__((address_space(1))) void*)g,
                                     (__attribute__((address_space(3))) void*)l, 16, 0, 0);
}

// ---------------------------------------------------------------- transpose
struct TDesc { const float* src; bfu* dst; int K, N, blk0; };
struct TPack { TDesc d[9]; };

__global__ __launch_bounds__(256) void transpose_k(TPack p) {
    const int bid = blockIdx.x;
    int j = 0;
#pragma unroll
    for (int i = 1; i < 9; ++i)
        if (bid >= p.d[i].blk0) j = i;
    const TDesc d = p.d[j];
    const int local = bid - d.blk0;
    const int tkn = d.K >> 6;
    const int tk = local % tkn, tn = local / tkn;
    const int k0 = tk * 64, n0 = tn * 64;
    __shared__ float tile[64][65];
    const int tx = threadIdx.x & 63, ty = threadIdx.x >> 6;
#pragma unroll
    for (int i = 0; i < 16; ++i) {
        const int r = ty * 16 + i;
        tile[r][tx] = d.src[(size_t)(k0 + r) * d.N + n0 + tx];
    }
    __syncthreads();
#pragma unroll
    for (int i = 0; i < 16; ++i) {
        const int n = ty * 16 + i;
        d.dst[(size_t)(n0 + n) * d.K + k0 + tx] = f2bf(tile[tx][n]);
    }
}

// ------------------------------------------------------- geometric + cast
__global__ __launch_bounds__(256)
void geomcast_k(const float* F0, const float* F1, bfu* D0, bfu* D1,
                float* g0, float* g1, float* p0, float* p1) {
    const int z = blockIdx.y;
    const float* F = z ? F1 : F0;
    bfu* D = z ? D1 : D0;
    float* gout = z ? g1 : g0;
    float* part = z ? p1 : p0;
    const int wave = threadIdx.x >> 6, lane = threadIdx.x & 63;
    const int row = blockIdx.x * 4 + wave;
    const float* fr = F + (size_t)row * 768;
    bfu* dr = D + (size_t)row * 768;
    float sum = 0.f, ss = 0.f, cnt = 0.f;
#pragma unroll
    for (int i = 0; i < 3; ++i) {
        const float4 v = *(const float4*)(fr + i * 256 + lane * 4);
        sum += v.x + v.y + v.z + v.w;
        ss += v.x * v.x + v.y * v.y + v.z * v.z + v.w * v.w;
        cnt += ((fabsf(v.x) > 0.01f) ? 1.f : 0.f) + ((fabsf(v.y) > 0.01f) ? 1.f : 0.f) +
               ((fabsf(v.z) > 0.01f) ? 1.f : 0.f) + ((fabsf(v.w) > 0.01f) ? 1.f : 0.f);
        ushort4 b;
        b.x = f2bf(v.x); b.y = f2bf(v.y); b.z = f2bf(v.z); b.w = f2bf(v.w);
        *(ushort4*)(dr + i * 256 + lane * 4) = b;
    }
#pragma unroll
    for (int off = 32; off; off >>= 1) {
        sum += __shfl_xor(sum, off);
        ss  += __shfl_xor(ss, off);
        cnt += __shfl_xor(cnt, off);
    }
    if (lane == 0) {
        const float n = sqrtf(ss);
        const float nq = sigm((n - 1.f) * 2.f);
        const float sp = cnt * (1.f / 768.f);
        float var = (ss - sum * sum * (1.f / 768.f)) * (1.f / 767.f);
        var = fmaxf(var, 0.f);
        const float sq = sigm(sqrtf(var) * 10.f - 1.f);
        gout[row] = (nq + sp + sq) * (1.f / 3.f);
        if (part) {
            const float cq = (n > 0.01f) ? (1.f / 768.f) : 0.f;
            const float nc = fmaxf(n, 1e-12f);
            const float dq = sigm(ss / (nc * nc) - 0.5f);
            part[row] = (cq + dq) * (1.f / 3.f);
        }
    }
}

// ------------------------------------------------------------------- GEMM
// Per-N-tile descriptor GEMM. Each 128-wide N-tile has its own A (staged),
// W rows, bias, and epilogue mode: 0 = store bf16+GELU, 1 = GELU then dot
// with dotw, row-reduce, atomicAdd into acc (head fusion, no C traffic).
// XCD swizzle: all N-tiles of an M-tile map to block ids with equal id%8 ->
// same XCD -> A-tile fetched once per XCD L2 (fixes round-2's 3x over-fetch).
struct Seg {
    const bfu* A; const bfu* A2;    // A2 supplies cols >= Ksplit (concat)
    const bfu* W;                    // this tile's W rows [128][K]
    const float* bias;               // per-col bias (tile-local)
    const float* dotw;               // mode1: dot weights (tile-local)
    bfu* C;                          // mode0: store base (tile-local cols)
    float* acc;                      // mode1: per-row fp32 accumulator
    int ldc; int mode;
};
struct SegPack { Seg s[12]; };

__global__ __launch_bounds__(256)
void gemm_k(SegPack p, int K, int Ksplit, int lda) {
    constexpr int BM = 128, BK = 64, MT = 4, NT = 4;
    __shared__ bfu As[BM * BK];
    __shared__ bfu Ws[128 * BK];
    const int NTt = gridDim.x;
    const int g = blockIdx.y * NTt + blockIdx.x;
    const int G8 = NTt * 8;                       // gridDim.y % 8 == 0 always
    const int m = (g / G8) * 8 + (g & 7);
    const int n = (g % G8) >> 3;
    const Seg sg = p.s[n];
    const int t = threadIdx.x;
    const int wave = t >> 6, lane = t & 63;
    const int row_l = lane & 15, kq = lane >> 4;
    const int m0 = m * BM;
    const int wm = wave >> 1, wn = wave & 1;
    const int wrow0 = wm * 64, wcol0 = wn * 64;

    f32x4 acc[MT][NT] = {};

    const int nkt = K / BK;
    for (int kt = 0; kt < nkt; ++kt) {
        const int k0 = kt * BK;
        const bfu* Ab;
        int kc;
        if (k0 < Ksplit) { Ab = sg.A; kc = k0; }
        else             { Ab = sg.A2; kc = k0 - Ksplit; }
#pragma unroll
        for (int i = 0; i < 4; ++i) {               // A tile 128x64
            const int c = i * 256 + t;
            const int r = c >> 3, s = c & 7;
            const int cc = (s ^ (r & 7)) << 3;      // XOR-swizzled source chunk
            async16(Ab + (size_t)(m0 + r) * lda + kc + cc, As + ((i * 256 + wave * 64) << 3));
        }
#pragma unroll
        for (int i = 0; i < 4; ++i) {               // W tile 128x64
            const int c = i * 256 + t;
            const int r = c >> 3, s = c & 7;
            const int cc = (s ^ (r & 7)) << 3;
            async16(sg.W + (size_t)r * K + k0 + cc, Ws + ((i * 256 + wave * 64) << 3));
        }
        __syncthreads();
#pragma unroll
        for (int ks = 0; ks < 2; ++ks) {
            bf16x8 af[MT], bfr[NT];
#pragma unroll
            for (int mi = 0; mi < MT; ++mi) {
                const int rA = wrow0 + mi * 16 + row_l;
                af[mi] = *(const bf16x8*)(As + rA * BK + (((ks * 4 + kq) ^ (rA & 7)) << 3));
            }
#pragma unroll
            for (int ni = 0; ni < NT; ++ni) {
                const int rB = wcol0 + ni * 16 + row_l;
                bfr[ni] = *(const bf16x8*)(Ws + rB * BK + (((ks * 4 + kq) ^ (rB & 7)) << 3));
            }
#pragma unroll
            for (int mi = 0; mi < MT; ++mi)
#pragma unroll
                for (int ni = 0; ni < NT; ++ni)
                    acc[mi][ni] = __builtin_amdgcn_mfma_f32_16x16x32_bf16(af[mi], bfr[ni], acc[mi][ni], 0, 0, 0);
        }
        __syncthreads();
    }

    // C/D layout: col=lane&15, row=quad*4+reg (m89/m91-verified)
    if (sg.mode == 0) {
#pragma unroll
        for (int ni = 0; ni < NT; ++ni) {
            const int col = wcol0 + ni * 16 + row_l;
            const float bv = sg.bias[col];
#pragma unroll
            for (int mi = 0; mi < MT; ++mi)
#pragma unroll
                for (int r = 0; r < 4; ++r) {
                    const int row = m0 + wrow0 + mi * 16 + kq * 4 + r;
                    sg.C[(size_t)row * sg.ldc + col] = f2bf(gelu_f(acc[mi][ni][r] + bv));
                }
        }
    } else {
#pragma unroll
        for (int mi = 0; mi < MT; ++mi)
#pragma unroll
            for (int r = 0; r < 4; ++r) {
                float s = 0.f;
#pragma unroll
                for (int ni = 0; ni < NT; ++ni) {
                    const int col = wcol0 + ni * 16 + row_l;
                    s += sg.dotw[col] * gelu_f(acc[mi][ni][r] + sg.bias[col]);
                }
                s += __shfl_xor(s, 1); s += __shfl_xor(s, 2);
                s += __shfl_xor(s, 4); s += __shfl_xor(s, 8);
                if (row_l == 0)
                    atomicAdd(sg.acc + m0 + wrow0 + mi * 16 + kq * 4 + r, s);
            }
    }
}

// ---------------------------------------- BN=64 GEMM + fused dot (disc l2)
__global__ __launch_bounds__(256)
void gemm64dot_k(const bfu* __restrict__ A, const bfu* __restrict__ W,
                 const float* __restrict__ bias, const float* __restrict__ dotw,
                 float* acc_out, int K, int lda) {
    constexpr int BK = 64, MT = 2, NT = 4;
    __shared__ bfu As[128 * BK];
    __shared__ bfu Ws[64 * BK];
    const int t = threadIdx.x;
    const int wave = t >> 6, lane = t & 63;
    const int row_l = lane & 15, kq = lane >> 4;
    const int m0 = blockIdx.x * 128;
    const int wrow0 = wave * 32;
    f32x4 acc[MT][NT] = {};
    const int nkt = K / BK;
    for (int kt = 0; kt < nkt; ++kt) {
        const int k0 = kt * BK;
#pragma unroll
        for (int i = 0; i < 4; ++i) {
            const int c = i * 256 + t;
            const int r = c >> 3, s = c & 7;
            const int cc = (s ^ (r & 7)) << 3;
            async16(A + (size_t)(m0 + r) * lda + k0 + cc, As + ((i * 256 + wave * 64) << 3));
        }
#pragma unroll
        for (int i = 0; i < 2; ++i) {
            const int c = i * 256 + t;
            const int r = c >> 3, s = c & 7;
            const int cc = (s ^ (r & 7)) << 3;
            async16(W + (size_t)r * K + k0 + cc, Ws + ((i * 256 + wave * 64) << 3));
        }
        __syncthreads();
#pragma unroll
        for (int ks = 0; ks < 2; ++ks) {
            bf16x8 af[MT], bfr[NT];
#pragma unroll
            for (int mi = 0; mi < MT; ++mi) {
                const int rA = wrow0 + mi * 16 + row_l;
                af[mi] = *(const bf16x8*)(As + rA * BK + (((ks * 4 + kq) ^ (rA & 7)) << 3));
            }
#pragma unroll
            for (int ni = 0; ni < NT; ++ni) {
                const int rB = ni * 16 + row_l;
                bfr[ni] = *(const bf16x8*)(Ws + rB * BK + (((ks * 4 + kq) ^ (rB & 7)) << 3));
            }
#pragma unroll
            for (int mi = 0; mi < MT; ++mi)
#pragma unroll
                for (int ni = 0; ni < NT; ++ni)
                    acc[mi][ni] = __builtin_amdgcn_mfma_f32_16x16x32_bf16(af[mi], bfr[ni], acc[mi][ni], 0, 0, 0);
        }
        __syncthreads();
    }
#pragma unroll
    for (int mi = 0; mi < MT; ++mi)
#pragma unroll
        for (int r = 0; r < 4; ++r) {
            float s = 0.f;
#pragma unroll
            for (int ni = 0; ni < NT; ++ni) {
                const int col = ni * 16 + row_l;
                s += dotw[col] * gelu_f(acc[mi][ni][r] + bias[col]);
            }
            s += __shfl_xor(s, 1); s += __shfl_xor(s, 2);
            s += __shfl_xor(s, 4); s += __shfl_xor(s, 8);
            if (row_l == 0)        // full 64-col dot in-wave: single writer
                acc_out[m0 + wrow0 + mi * 16 + kq * 4 + r] = s;
        }
}

// -------------------------------- BN=64 GEMM + fused entropy (info l2)
__global__ __launch_bounds__(256)
void gemm64ent_k(const bfu* __restrict__ A, const bfu* __restrict__ W,
                 const float* __restrict__ bias, const float* __restrict__ part,
                 float* out, int B, int K, int lda) {
    constexpr int BK = 64, MT = 2, NT = 4;
    __shared__ __align__(16) float smemf[8320];   // 33280 B: staging | ET union
    bfu* As = (bfu*)smemf;                        // 128x64 bf16 = 16 KB
    bfu* Ws = (bfu*)smemf + 128 * BK;             // 64x64 bf16 = 8 KB
    float* ET = smemf;                            // 128 x 65 fp32 after K-loop
    const int t = threadIdx.x;
    const int wave = t >> 6, lane = t & 63;
    const int row_l = lane & 15, kq = lane >> 4;
    const int m0 = blockIdx.x * 128;
    const int wrow0 = wave * 32;
    f32x4 acc[MT][NT] = {};
    const int nkt = K / BK;
    for (int kt = 0; kt < nkt; ++kt) {
        const int k0 = kt * BK;
#pragma unroll
        for (int i = 0; i < 4; ++i) {
            const int c = i * 256 + t;
            const int r = c >> 3, s = c & 7;
            const int cc = (s ^ (r & 7)) << 3;
            async16(A + (size_t)(m0 + r) * lda + k0 + cc, As + ((i * 256 + wave * 64) << 3));
        }
#pragma unroll
        for (int i = 0; i < 2; ++i) {
            const int c = i * 256 + t;
            const int r = c >> 3, s = c & 7;
            const int cc = (s ^ (r & 7)) << 3;
            async16(W + (size_t)r * K + k0 + cc, Ws + ((i * 256 + wave * 64) << 3));
        }
        __syncthreads();
#pragma unroll
        for (int ks = 0; ks < 2; ++ks) {
            bf16x8 af[MT], bfr[NT];
#pragma unroll
            for (int mi = 0; mi < MT; ++mi) {
                const int rA = wrow0 + mi * 16 + row_l;
                af[mi] = *(const bf16x8*)(As + rA * BK + (((ks * 4 + kq) ^ (rA & 7)) << 3));
            }
#pragma unroll
            for (int ni = 0; ni < NT; ++ni) {
                const int rB = ni * 16 + row_l;
                bfr[ni] = *(const bf16x8*)(Ws + rB * BK + (((ks * 4 + kq) ^ (rB & 7)) << 3));
            }
#pragma unroll
            for (int mi = 0; mi < MT; ++mi)
#pragma unroll
                for (int ni = 0; ni < NT; ++ni)
                    acc[mi][ni] = __builtin_amdgcn_mfma_f32_16x16x32_bf16(af[mi], bfr[ni], acc[mi][ni], 0, 0, 0);
        }
        __syncthreads();
    }
    // dump 128x64 fp32 logits (no activation) to LDS
#pragma unroll
    for (int mi = 0; mi < MT; ++mi)
#pragma unroll
        for (int ni = 0; ni < NT; ++ni) {
            const int col = ni * 16 + row_l;
            const float bv = bias[col];
#pragma unroll
            for (int r = 0; r < 4; ++r)
                ET[(wrow0 + mi * 16 + kq * 4 + r) * 65 + col] = acc[mi][ni][r] + bv;
        }
    __syncthreads();
    if (t < 128) {   // one thread per row: histogram entropy over 64 logits
        int cnt[11];
#pragma unroll
        for (int b = 0; b < 11; ++b) cnt[b] = 0;
        for (int j = 0; j < 64; ++j) {
            const int d = (int)rintf(sigm(ET[t * 65 + j]) * 10.f);
#pragma unroll
            for (int b = 0; b < 11; ++b) cnt[b] += (d == b);
        }
        float ent = 0.f;
#pragma unroll
        for (int b = 0; b < 11; ++b) {
            if (cnt[b] > 0) {
                const float pp = (float)cnt[b] * (1.f / 64.f);
                ent -= pp * __logf(pp + 1e-8f);
            }
        }
        const int row = m0 + t;
        const int orow = (row < B) ? 4 : 5;
        const int rl = (row < B) ? row : row - B;
        out[(size_t)orow * B + rl] = part[row] + sigm(ent - 2.f) * (1.f / 3.f);
    }
}

__global__ __launch_bounds__(256) void zero_k(float* p, int n) {
    const int i = blockIdx.x * 256 + threadIdx.x;
    if (i < n) p[i] = 0.f;
}

// --------------- finalize: sigmoids over fused-dot accumulators + overall
__global__ __launch_bounds__(256)
void finalize_k(float* out, const float* a_imp1, const float* a_imp2,
                const float* a_co, const float* a_ce, const float* a_df,
                const float* a_d1, const float* a_d2,
                const float* imp_b2, const float* disc_b3,
                const float* cons_b3, const float* diff_b3, int B) {
    const int i = blockIdx.x * 256 + threadIdx.x;
    if (i >= B) return;
    const float ib = imp_b2[0], db = disc_b3[0], cb = cons_b3[0], fb = diff_b3[0];
    const float o6 = sigm(a_co[i] + cb);
    const float o7 = sigm(a_ce[i] + cb);
    const float o8 = sigm(a_imp1[i] + ib);
    const float o9 = sigm(a_imp1[B + i] + ib);
    out[6 * B + i] = o6;
    out[7 * B + i] = o7;
    out[8 * B + i] = o8;
    out[9 * B + i] = o9;
    out[10 * B + i] = sigm(a_imp2[i] + ib);
    out[11 * B + i] = sigm(a_imp2[B + i] + ib);
    out[12 * B + i] = sigm(a_d1[i] + db);
    out[14 * B + i] = sigm(a_d1[B + i] + db);
    out[13 * B + i] = sigm(a_d2[i] + db);
    out[15 * B + i] = sigm(a_d2[B + i] + db);
    out[16 * B + i] = sigm(a_df[i] + fb);
    const float v = out[0 * B + i] + out[1 * B + i] + out[4 * B + i] + out[5 * B + i] +
                    o7 + 0.5f * (o8 + o9);
    out[17 * B + i] = v * (1.f / 6.f);
}

extern "C" void kernel_launch(void* const* d_in, const int* in_sizes, int n_in,
                              void* d_out, int out_size, void* d_ws, size_t ws_size,
                              hipStream_t stream) {
    const int B = in_sizes[4];  // 16384
    const int B2 = 2 * B;
    float* out = (float*)d_out;
    const float* img  = (const float*)d_in[0];
    const float* txt  = (const float*)d_in[1];
    const float* eimg = (const float*)d_in[2];
    const float* etxt = (const float*)d_in[3];
    const float* info_w1 = (const float*)d_in[5];  const float* info_b1 = (const float*)d_in[6];
    const float* info_w2 = (const float*)d_in[7];  const float* info_b2 = (const float*)d_in[8];
    const float* imp_w1  = (const float*)d_in[9];  const float* imp_b1  = (const float*)d_in[10];
    const float* imp_w2  = (const float*)d_in[11]; const float* imp_b2  = (const float*)d_in[12];
    const float* disc_w1 = (const float*)d_in[13]; const float* disc_b1 = (const float*)d_in[14];
    const float* disc_w2 = (const float*)d_in[15]; const float* disc_b2 = (const float*)d_in[16];
    const float* disc_w3 = (const float*)d_in[17]; const float* disc_b3 = (const float*)d_in[18];
    const float* cons_w1 = (const float*)d_in[19]; const float* cons_b1 = (const float*)d_in[20];
    const float* cons_w2 = (const float*)d_in[21]; const float* cons_b2 = (const float*)d_in[22];
    const float* cons_w3 = (const float*)d_in[23]; const float* cons_b3 = (const float*)d_in[24];
    const float* diff_w1 = (const float*)d_in[25]; const float* diff_b1 = (const float*)d_in[26];
    const float* diff_w2 = (const float*)d_in[27]; const float* diff_b2 = (const float*)d_in[28];
    const float* diff_w3 = (const float*)d_in[29]; const float* diff_b3 = (const float*)d_in[30];

    char* wsp = (char*)d_ws;
    size_t off = 0;
    auto alloc = [&](size_t bytes) -> void* {
        void* p = wsp + off;
        off += (bytes + 255) & ~(size_t)255;
        return p;
    };
    // bf16 transposed weights [N][K]
    bfu* info1t = (bfu*)alloc((size_t)256 * 768 * 2);
    bfu* info2t = (bfu*)alloc((size_t)64 * 256 * 2);
    bfu* imp1t  = (bfu*)alloc((size_t)384 * 768 * 2);
    bfu* disc1t = (bfu*)alloc((size_t)256 * 768 * 2);
    bfu* disc2t = (bfu*)alloc((size_t)64 * 256 * 2);
    bfu* cons1t = (bfu*)alloc((size_t)768 * 1536 * 2);
    bfu* cons2t = (bfu*)alloc((size_t)384 * 768 * 2);
    bfu* diff1t = (bfu*)alloc((size_t)768 * 1536 * 2);
    bfu* diff2t = (bfu*)alloc((size_t)384 * 768 * 2);
    float* part = (float*)alloc((size_t)B2 * 4);
    // head accumulators: [imp1 2B][imp2 2B][cons_o B][cons_e B][diff B] zeroed,
    // then [disc1 2B][disc2 2B] direct-stored.
    float* accz = (float*)alloc((size_t)(7 * B + 4 * B) * 4);
    float* a_imp1 = accz;
    float* a_imp2 = accz + B2;
    float* a_co = accz + 2 * B2;
    float* a_ce = a_co + B;
    float* a_df = a_ce + B;
    float* a_d1 = a_df + B;
    float* a_d2 = a_d1 + B2;
    bfu* fA01 = (bfu*)alloc((size_t)B2 * 768 * 2);           // 50.3 MB
    bfu* X    = (bfu*)alloc((size_t)B2 * 768 * 2);           // 50.3 MB scratch
    bfu* Hi   = X;                                           // [2B x 256]
    bfu* Hd   = X + (size_t)B2 * 256;                        // [2B x 256]
    bfu* Hc_c = X;                                           // [B x 768] later
    bfu* Hc_d = X + (size_t)B * 768;                         // [B x 768] later
    (void)ws_size; (void)n_in; (void)out_size;  // ~111 MB total

    zero_k<<<dim3((7 * B + 255) / 256), 256, 0, stream>>>(accz, 7 * B);

    TPack tp;
    int blk = 0, ti = 0;
    auto setd = [&](const float* s, bfu* d, int K, int N) {
        tp.d[ti++] = {s, d, K, N, blk};
        blk += (K / 64) * (N / 64);
    };
    setd(info_w1, info1t, 768, 256);
    setd(info_w2, info2t, 256, 64);
    setd(imp_w1, imp1t, 768, 384);
    setd(disc_w1, disc1t, 768, 256);
    setd(disc_w2, disc2t, 256, 64);
    setd(cons_w1, cons1t, 1536, 768);
    setd(cons_w2, cons2t, 768, 384);
    setd(diff_w1, diff1t, 1536, 768);
    setd(diff_w2, diff2t, 768, 384);
    transpose_k<<<dim3(blk), 256, 0, stream>>>(tp);

    auto store_seg = [&](const bfu* A, const bfu* A2, const bfu* W, const float* b,
                         bfu* C, int ldc) -> Seg {
        return Seg{A, A2, W, b, nullptr, C, nullptr, ldc, 0};
    };
    auto dot_seg = [&](const bfu* A, const bfu* A2, const bfu* W, const float* b,
                       const float* dw, float* acc) -> Seg {
        return Seg{A, A2, W, b, dw, nullptr, acc, 0, 1};
    };
    const bfu* fB = fA01 + (size_t)B * 768;

    // ================= phase 1: image / text =================
    geomcast_k<<<dim3(B / 4, 2), 256, 0, stream>>>(img, txt, fA01, (bfu*)fB,
                                                   out + 0 * B, out + 1 * B, part, part + B);
    {   // fused info1 | imp1(+dot) | disc1 over shared A, N=896 (7 tiles)
        SegPack p;
        p.s[0] = store_seg(fA01, fA01, info1t, info_b1, Hi, 256);
        p.s[1] = store_seg(fA01, fA01, info1t + (size_t)128 * 768, info_b1 + 128, Hi + 128, 256);
        for (int i = 0; i < 3; ++i)
            p.s[2 + i] = dot_seg(fA01, fA01, imp1t + (size_t)128 * i * 768,
                                 imp_b1 + 128 * i, imp_w2 + 128 * i, a_imp1);
        p.s[5] = store_seg(fA01, fA01, disc1t, disc_b1, Hd, 256);
        p.s[6] = store_seg(fA01, fA01, disc1t + (size_t)128 * 768, disc_b1 + 128, Hd + 128, 256);
        for (int i = 7; i < 12; ++i) p.s[i] = p.s[0];
        gemm_k<<<dim3(7, B2 / 128), 256, 0, stream>>>(p, 768, 768, 768);
    }
    gemm64ent_k<<<dim3(B2 / 128), 256, 0, stream>>>(Hi, info2t, info_b2, part, out, B, 256, 256);
    gemm64dot_k<<<dim3(B2 / 128), 256, 0, stream>>>(Hd, disc2t, disc_b2, disc_w3, a_d1, 256, 256);
    {   // cons_o layer1: concat A, N=768 (6 store tiles) -> Hc_c
        SegPack p;
        for (int i = 0; i < 6; ++i)
            p.s[i] = store_seg(fA01, fB, cons1t + (size_t)128 * i * 1536,
                               cons_b1 + 128 * i, Hc_c + 128 * i, 768);
        for (int i = 6; i < 12; ++i) p.s[i] = p.s[0];
        gemm_k<<<dim3(6, B / 128), 256, 0, stream>>>(p, 1536, 768, 768);
    }
    {   // cons_o layer2 + dot
        SegPack p;
        for (int i = 0; i < 3; ++i)
            p.s[i] = dot_seg(Hc_c, Hc_c, cons2t + (size_t)128 * i * 768,
                             cons_b2 + 128 * i, cons_w3 + 128 * i, a_co);
        for (int i = 3; i < 12; ++i) p.s[i] = p.s[0];
        gemm_k<<<dim3(3, B / 128), 256, 0, stream>>>(p, 768, 768, 768);
    }

    // ================= phase 2: enhanced image / text =================
    geomcast_k<<<dim3(B / 4, 2), 256, 0, stream>>>(eimg, etxt, fA01, (bfu*)fB,
                                                   out + 2 * B, out + 3 * B, nullptr, nullptr);
    {   // fused imp1(+dot) | disc1, N=640 (5 tiles)
        SegPack p;
        for (int i = 0; i < 3; ++i)
            p.s[i] = dot_seg(fA01, fA01, imp1t + (size_t)128 * i * 768,
                             imp_b1 + 128 * i, imp_w2 + 128 * i, a_imp2);
        p.s[3] = store_seg(fA01, fA01, disc1t, disc_b1, Hd, 256);
        p.s[4] = store_seg(fA01, fA01, disc1t + (size_t)128 * 768, disc_b1 + 128, Hd + 128, 256);
        for (int i = 5; i < 12; ++i) p.s[i] = p.s[0];
        gemm_k<<<dim3(5, B2 / 128), 256, 0, stream>>>(p, 768, 768, 768);
    }
    gemm64dot_k<<<dim3(B2 / 128), 256, 0, stream>>>(Hd, disc2t, disc_b2, disc_w3, a_d2, 256, 256);
    {   // cons_e + diff layer1 fused: shared concat A, N=1536 (12 tiles)
        SegPack p;
        for (int i = 0; i < 6; ++i) {
            p.s[i]     = store_seg(fA01, fB, cons1t + (size_t)128 * i * 1536,
                                   cons_b1 + 128 * i, Hc_c + 128 * i, 768);
            p.s[6 + i] = store_seg(fA01, fB, diff1t + (size_t)128 * i * 1536,
                                   diff_b1 + 128 * i, Hc_d + 128 * i, 768);
        }
        gemm_k<<<dim3(12, B / 128), 256, 0, stream>>>(p, 1536, 768, 768);
    }
    {   // cons_e l2+dot | diff l2+dot (per-seg A)
        SegPack p;
        for (int i = 0; i < 3; ++i) {
            p.s[i]     = dot_seg(Hc_c, Hc_c, cons2t + (size_t)128 * i * 768,
                                 cons_b2 + 128 * i, cons_w3 + 128 * i, a_ce);
            p.s[3 + i] = dot_seg(Hc_d, Hc_d, diff2t + (size_t)128 * i * 768,
                                 diff_b2 + 128 * i, diff_w3 + 128 * i, a_df);
        }
        for (int i = 6; i < 12; ++i) p.s[i] = p.s[0];
        gemm_k<<<dim3(6, B / 128), 256, 0, stream>>>(p, 768, 768, 768);
    }

    finalize_k<<<dim3((B + 255) / 256), 256, 0, stream>>>(out, a_imp1, a_imp2, a_co, a_ce,
                                                          a_df, a_d1, a_d2,
                                                          imp_b2, disc_b3, cons_b3, diff_b3, B);
}

// Round 4
// 730.466 us; speedup vs baseline: 1.2939x; 1.0994x over previous
//
#include <hip/hip_runtime.h>

typedef unsigned short bfu;                                     // bf16 storage
typedef __attribute__((ext_vector_type(8))) __bf16 bf16x8;      // MFMA A/B frag
typedef __attribute__((ext_vector_type(4))) float f32x4;        // MFMA C/D frag

__device__ __forceinline__ float bf2f(bfu u) {
    unsigned int x = ((unsigned int)u) << 16;
    return __builtin_bit_cast(float, x);
}
__device__ __forceinline__ bfu f2bf(float f) {  // round-nearest-even
    unsigned int u = __builtin_bit_cast(unsigned int, f);
    unsigned int r = (u + 0x7fffu + ((u >> 16) & 1u)) >> 16;
    return (bfu)r;
}
__device__ __forceinline__ float sigm(float x) { return 1.0f / (1.0f + __expf(-x)); }
// fast tanh-GELU (~1e-3 abs err): epilogue was VALU-bound on erff (R3: VALUBusy
// 52% vs MfmaUtil 24%); one __expf replaces the ~25-op erf polynomial.
__device__ __forceinline__ float gelu_f(float x) {
    const float y = 0.7978845608f * (x + 0.044715f * x * x * x);
    const float t = 1.f - 2.f / (__expf(2.f * y) + 1.f);
    return 0.5f * x * (1.f + t);
}
// exact erf GELU: info head only (its round(sig*10) histogram is discontinuous;
// 1e-3 logit shifts flip bins worth 6.7e-3 each in the output)
__device__ __forceinline__ float gelu_x(float x) {
    return 0.5f * x * (1.0f + erff(x * 0.70710678118654752f));
}

// async global->LDS, 16B/lane; LDS dest = wave-uniform base + lane*16.
__device__ __forceinline__ void async16(const void* g, void* l) {
    __builtin_amdgcn_global_load_lds((const __attribute__((address_space(1))) void*)g,
                                     (__attribute__((address_space(3))) void*)l, 16, 0, 0);
}

// ---------------------------------------------------------------- transpose
struct TDesc { const float* src; bfu* dst; int K, N, blk0; };
struct TPack { TDesc d[9]; };

__global__ __launch_bounds__(256) void transpose_k(TPack p) {
    const int bid = blockIdx.x;
    int j = 0;
#pragma unroll
    for (int i = 1; i < 9; ++i)
        if (bid >= p.d[i].blk0) j = i;
    const TDesc d = p.d[j];
    const int local = bid - d.blk0;
    const int tkn = d.K >> 6;
    const int tk = local % tkn, tn = local / tkn;
    const int k0 = tk * 64, n0 = tn * 64;
    __shared__ float tile[64][65];
    const int tx = threadIdx.x & 63, ty = threadIdx.x >> 6;
#pragma unroll
    for (int i = 0; i < 16; ++i) {
        const int r = ty * 16 + i;
        tile[r][tx] = d.src[(size_t)(k0 + r) * d.N + n0 + tx];
    }
    __syncthreads();
#pragma unroll
    for (int i = 0; i < 16; ++i) {
        const int n = ty * 16 + i;
        d.dst[(size_t)(n0 + n) * d.K + k0 + tx] = f2bf(tile[tx][n]);
    }
}

// ------------------------------------------------------- geometric + cast
__global__ __launch_bounds__(256)
void geomcast_k(const float* F0, const float* F1, bfu* D0, bfu* D1,
                float* g0, float* g1, float* p0, float* p1) {
    const int z = blockIdx.y;
    const float* F = z ? F1 : F0;
    bfu* D = z ? D1 : D0;
    float* gout = z ? g1 : g0;
    float* part = z ? p1 : p0;
    const int wave = threadIdx.x >> 6, lane = threadIdx.x & 63;
    const int row = blockIdx.x * 4 + wave;
    const float* fr = F + (size_t)row * 768;
    bfu* dr = D + (size_t)row * 768;
    float sum = 0.f, ss = 0.f, cnt = 0.f;
#pragma unroll
    for (int i = 0; i < 3; ++i) {
        const float4 v = *(const float4*)(fr + i * 256 + lane * 4);
        sum += v.x + v.y + v.z + v.w;
        ss += v.x * v.x + v.y * v.y + v.z * v.z + v.w * v.w;
        cnt += ((fabsf(v.x) > 0.01f) ? 1.f : 0.f) + ((fabsf(v.y) > 0.01f) ? 1.f : 0.f) +
               ((fabsf(v.z) > 0.01f) ? 1.f : 0.f) + ((fabsf(v.w) > 0.01f) ? 1.f : 0.f);
        ushort4 b;
        b.x = f2bf(v.x); b.y = f2bf(v.y); b.z = f2bf(v.z); b.w = f2bf(v.w);
        *(ushort4*)(dr + i * 256 + lane * 4) = b;
    }
#pragma unroll
    for (int off = 32; off; off >>= 1) {
        sum += __shfl_xor(sum, off);
        ss  += __shfl_xor(ss, off);
        cnt += __shfl_xor(cnt, off);
    }
    if (lane == 0) {
        const float n = sqrtf(ss);
        const float nq = sigm((n - 1.f) * 2.f);
        const float sp = cnt * (1.f / 768.f);
        float var = (ss - sum * sum * (1.f / 768.f)) * (1.f / 767.f);
        var = fmaxf(var, 0.f);
        const float sq = sigm(sqrtf(var) * 10.f - 1.f);
        gout[row] = (nq + sp + sq) * (1.f / 3.f);
        if (part) {
            const float cq = (n > 0.01f) ? (1.f / 768.f) : 0.f;
            const float nc = fmaxf(n, 1e-12f);
            const float dq = sigm(ss / (nc * nc) - 0.5f);
            part[row] = (cq + dq) * (1.f / 3.f);
        }
    }
}

// ------------------------------------------------------------------- GEMM
// Per-N-tile descriptor GEMM. mode 0 = store bf16 + fast GELU; mode 2 =
// store bf16 + exact-erf GELU (info head); mode 1 = fast GELU then dot with
// dotw, row-reduce, atomicAdd into acc (head fusion, no C traffic).
// XCD swizzle: all N-tiles of an M-tile share id%8 -> same XCD -> A fetched
// once per XCD L2 (R3: FETCH 157->83 MB).
struct Seg {
    const bfu* A; const bfu* A2;    // A2 supplies cols >= Ksplit (concat)
    const bfu* W;                    // this tile's W rows [128][K]
    const float* bias;               // per-col bias (tile-local)
    const float* dotw;               // mode1: dot weights (tile-local)
    bfu* C;                          // mode0/2: store base (tile-local cols)
    float* acc;                      // mode1: per-row fp32 accumulator
    int ldc; int mode;
};
struct SegPack { Seg s[12]; };

__global__ __launch_bounds__(256)
void gemm_k(SegPack p, int K, int Ksplit, int lda) {
    constexpr int BM = 128, BK = 64, MT = 4, NT = 4;
    __shared__ bfu As[BM * BK];
    __shared__ bfu Ws[128 * BK];
    const int NTt = gridDim.x;
    const int g = blockIdx.y * NTt + blockIdx.x;
    const int G8 = NTt * 8;                       // gridDim.y % 8 == 0 always
    const int m = (g / G8) * 8 + (g & 7);
    const int n = (g % G8) >> 3;
    const Seg sg = p.s[n];
    const int t = threadIdx.x;
    const int wave = t >> 6, lane = t & 63;
    const int row_l = lane & 15, kq = lane >> 4;
    const int m0 = m * BM;
    const int wm = wave >> 1, wn = wave & 1;
    const int wrow0 = wm * 64, wcol0 = wn * 64;

    f32x4 acc[MT][NT] = {};

    const int nkt = K / BK;
    for (int kt = 0; kt < nkt; ++kt) {
        const int k0 = kt * BK;
        const bfu* Ab;
        int kc;
        if (k0 < Ksplit) { Ab = sg.A; kc = k0; }
        else             { Ab = sg.A2; kc = k0 - Ksplit; }
#pragma unroll
        for (int i = 0; i < 4; ++i) {               // A tile 128x64
            const int c = i * 256 + t;
            const int r = c >> 3, s = c & 7;
            const int cc = (s ^ (r & 7)) << 3;      // XOR-swizzled source chunk
            async16(Ab + (size_t)(m0 + r) * lda + kc + cc, As + ((i * 256 + wave * 64) << 3));
        }
#pragma unroll
        for (int i = 0; i < 4; ++i) {               // W tile 128x64
            const int c = i * 256 + t;
            const int r = c >> 3, s = c & 7;
            const int cc = (s ^ (r & 7)) << 3;
            async16(sg.W + (size_t)r * K + k0 + cc, Ws + ((i * 256 + wave * 64) << 3));
        }
        __syncthreads();
#pragma unroll
        for (int ks = 0; ks < 2; ++ks) {
            bf16x8 af[MT], bfr[NT];
#pragma unroll
            for (int mi = 0; mi < MT; ++mi) {
                const int rA = wrow0 + mi * 16 + row_l;
                af[mi] = *(const bf16x8*)(As + rA * BK + (((ks * 4 + kq) ^ (rA & 7)) << 3));
            }
#pragma unroll
            for (int ni = 0; ni < NT; ++ni) {
                const int rB = wcol0 + ni * 16 + row_l;
                bfr[ni] = *(const bf16x8*)(Ws + rB * BK + (((ks * 4 + kq) ^ (rB & 7)) << 3));
            }
#pragma unroll
            for (int mi = 0; mi < MT; ++mi)
#pragma unroll
                for (int ni = 0; ni < NT; ++ni)
                    acc[mi][ni] = __builtin_amdgcn_mfma_f32_16x16x32_bf16(af[mi], bfr[ni], acc[mi][ni], 0, 0, 0);
        }
        __syncthreads();
    }

    // C/D layout: col=lane&15, row=quad*4+reg (m89/m91-verified)
    if (sg.mode == 0) {
#pragma unroll
        for (int ni = 0; ni < NT; ++ni) {
            const int col = wcol0 + ni * 16 + row_l;
            const float bv = sg.bias[col];
#pragma unroll
            for (int mi = 0; mi < MT; ++mi)
#pragma unroll
                for (int r = 0; r < 4; ++r) {
                    const int row = m0 + wrow0 + mi * 16 + kq * 4 + r;
                    sg.C[(size_t)row * sg.ldc + col] = f2bf(gelu_f(acc[mi][ni][r] + bv));
                }
        }
    } else if (sg.mode == 2) {
#pragma unroll
        for (int ni = 0; ni < NT; ++ni) {
            const int col = wcol0 + ni * 16 + row_l;
            const float bv = sg.bias[col];
#pragma unroll
            for (int mi = 0; mi < MT; ++mi)
#pragma unroll
                for (int r = 0; r < 4; ++r) {
                    const int row = m0 + wrow0 + mi * 16 + kq * 4 + r;
                    sg.C[(size_t)row * sg.ldc + col] = f2bf(gelu_x(acc[mi][ni][r] + bv));
                }
        }
    } else {
#pragma unroll
        for (int mi = 0; mi < MT; ++mi)
#pragma unroll
            for (int r = 0; r < 4; ++r) {
                float s = 0.f;
#pragma unroll
                for (int ni = 0; ni < NT; ++ni) {
                    const int col = wcol0 + ni * 16 + row_l;
                    s += sg.dotw[col] * gelu_f(acc[mi][ni][r] + sg.bias[col]);
                }
                s += __shfl_xor(s, 1); s += __shfl_xor(s, 2);
                s += __shfl_xor(s, 4); s += __shfl_xor(s, 8);
                if (row_l == 0)
                    atomicAdd(sg.acc + m0 + wrow0 + mi * 16 + kq * 4 + r, s);
            }
    }
}

// ---------------------------------------- BN=64 GEMM + fused dot (disc l2)
__global__ __launch_bounds__(256)
void gemm64dot_k(const bfu* __restrict__ A, const bfu* __restrict__ W,
                 const float* __restrict__ bias, const float* __restrict__ dotw,
                 float* acc_out, int K, int lda) {
    constexpr int BK = 64, MT = 2, NT = 4;
    __shared__ bfu As[128 * BK];
    __shared__ bfu Ws[64 * BK];
    const int t = threadIdx.x;
    const int wave = t >> 6, lane = t & 63;
    const int row_l = lane & 15, kq = lane >> 4;
    const int m0 = blockIdx.x * 128;
    const int wrow0 = wave * 32;
    f32x4 acc[MT][NT] = {};
    const int nkt = K / BK;
    for (int kt = 0; kt < nkt; ++kt) {
        const int k0 = kt * BK;
#pragma unroll
        for (int i = 0; i < 4; ++i) {
            const int c = i * 256 + t;
            const int r = c >> 3, s = c & 7;
            const int cc = (s ^ (r & 7)) << 3;
            async16(A + (size_t)(m0 + r) * lda + k0 + cc, As + ((i * 256 + wave * 64) << 3));
        }
#pragma unroll
        for (int i = 0; i < 2; ++i) {
            const int c = i * 256 + t;
            const int r = c >> 3, s = c & 7;
            const int cc = (s ^ (r & 7)) << 3;
            async16(W + (size_t)r * K + k0 + cc, Ws + ((i * 256 + wave * 64) << 3));
        }
        __syncthreads();
#pragma unroll
        for (int ks = 0; ks < 2; ++ks) {
            bf16x8 af[MT], bfr[NT];
#pragma unroll
            for (int mi = 0; mi < MT; ++mi) {
                const int rA = wrow0 + mi * 16 + row_l;
                af[mi] = *(const bf16x8*)(As + rA * BK + (((ks * 4 + kq) ^ (rA & 7)) << 3));
            }
#pragma unroll
            for (int ni = 0; ni < NT; ++ni) {
                const int rB = ni * 16 + row_l;
                bfr[ni] = *(const bf16x8*)(Ws + rB * BK + (((ks * 4 + kq) ^ (rB & 7)) << 3));
            }
#pragma unroll
            for (int mi = 0; mi < MT; ++mi)
#pragma unroll
                for (int ni = 0; ni < NT; ++ni)
                    acc[mi][ni] = __builtin_amdgcn_mfma_f32_16x16x32_bf16(af[mi], bfr[ni], acc[mi][ni], 0, 0, 0);
        }
        __syncthreads();
    }
#pragma unroll
    for (int mi = 0; mi < MT; ++mi)
#pragma unroll
        for (int r = 0; r < 4; ++r) {
            float s = 0.f;
#pragma unroll
            for (int ni = 0; ni < NT; ++ni) {
                const int col = ni * 16 + row_l;
                s += dotw[col] * gelu_f(acc[mi][ni][r] + bias[col]);
            }
            s += __shfl_xor(s, 1); s += __shfl_xor(s, 2);
            s += __shfl_xor(s, 4); s += __shfl_xor(s, 8);
            if (row_l == 0)        // full 64-col dot in-wave: single writer
                acc_out[m0 + wrow0 + mi * 16 + kq * 4 + r] = s;
        }
}

// -------------------------------- BN=64 GEMM + fused entropy (info l2)
__global__ __launch_bounds__(256)
void gemm64ent_k(const bfu* __restrict__ A, const bfu* __restrict__ W,
                 const float* __restrict__ bias, const float* __restrict__ part,
                 float* out, int B, int K, int lda) {
    constexpr int BK = 64, MT = 2, NT = 4;
    __shared__ __align__(16) float smemf[8320];   // 33280 B: staging | ET union
    bfu* As = (bfu*)smemf;                        // 128x64 bf16 = 16 KB
    bfu* Ws = (bfu*)smemf + 128 * BK;             // 64x64 bf16 = 8 KB
    float* ET = smemf;                            // 128 x 65 fp32 after K-loop
    const int t = threadIdx.x;
    const int wave = t >> 6, lane = t & 63;
    const int row_l = lane & 15, kq = lane >> 4;
    const int m0 = blockIdx.x * 128;
    const int wrow0 = wave * 32;
    f32x4 acc[MT][NT] = {};
    const int nkt = K / BK;
    for (int kt = 0; kt < nkt; ++kt) {
        const int k0 = kt * BK;
#pragma unroll
        for (int i = 0; i < 4; ++i) {
            const int c = i * 256 + t;
            const int r = c >> 3, s = c & 7;
            const int cc = (s ^ (r & 7)) << 3;
            async16(A + (size_t)(m0 + r) * lda + k0 + cc, As + ((i * 256 + wave * 64) << 3));
        }
#pragma unroll
        for (int i = 0; i < 2; ++i) {
            const int c = i * 256 + t;
            const int r = c >> 3, s = c & 7;
            const int cc = (s ^ (r & 7)) << 3;
            async16(W + (size_t)r * K + k0 + cc, Ws + ((i * 256 + wave * 64) << 3));
        }
        __syncthreads();
#pragma unroll
        for (int ks = 0; ks < 2; ++ks) {
            bf16x8 af[MT], bfr[NT];
#pragma unroll
            for (int mi = 0; mi < MT; ++mi) {
                const int rA = wrow0 + mi * 16 + row_l;
                af[mi] = *(const bf16x8*)(As + rA * BK + (((ks * 4 + kq) ^ (rA & 7)) << 3));
            }
#pragma unroll
            for (int ni = 0; ni < NT; ++ni) {
                const int rB = ni * 16 + row_l;
                bfr[ni] = *(const bf16x8*)(Ws + rB * BK + (((ks * 4 + kq) ^ (rB & 7)) << 3));
            }
#pragma unroll
            for (int mi = 0; mi < MT; ++mi)
#pragma unroll
                for (int ni = 0; ni < NT; ++ni)
                    acc[mi][ni] = __builtin_amdgcn_mfma_f32_16x16x32_bf16(af[mi], bfr[ni], acc[mi][ni], 0, 0, 0);
        }
        __syncthreads();
    }
    // dump 128x64 fp32 logits (no activation) to LDS
#pragma unroll
    for (int mi = 0; mi < MT; ++mi)
#pragma unroll
        for (int ni = 0; ni < NT; ++ni) {
            const int col = ni * 16 + row_l;
            const float bv = bias[col];
#pragma unroll
            for (int r = 0; r < 4; ++r)
                ET[(wrow0 + mi * 16 + kq * 4 + r) * 65 + col] = acc[mi][ni][r] + bv;
        }
    __syncthreads();
    if (t < 128) {   // one thread per row: histogram entropy over 64 logits
        int cnt[11];
#pragma unroll
        for (int b = 0; b < 11; ++b) cnt[b] = 0;
        for (int j = 0; j < 64; ++j) {
            const int d = (int)rintf(sigm(ET[t * 65 + j]) * 10.f);
#pragma unroll
            for (int b = 0; b < 11; ++b) cnt[b] += (d == b);
        }
        float ent = 0.f;
#pragma unroll
        for (int b = 0; b < 11; ++b) {
            if (cnt[b] > 0) {
                const float pp = (float)cnt[b] * (1.f / 64.f);
                ent -= pp * __logf(pp + 1e-8f);
            }
        }
        const int row = m0 + t;
        const int orow = (row < B) ? 4 : 5;
        const int rl = (row < B) ? row : row - B;
        out[(size_t)orow * B + rl] = part[row] + sigm(ent - 2.f) * (1.f / 3.f);
    }
}

__global__ __launch_bounds__(256) void zero_k(float* p, int n) {
    const int i = blockIdx.x * 256 + threadIdx.x;
    if (i < n) p[i] = 0.f;
}

// --------------- finalize: sigmoids over fused-dot accumulators + overall
__global__ __launch_bounds__(256)
void finalize_k(float* out, const float* a_imp1, const float* a_imp2,
                const float* a_co, const float* a_ce, const float* a_df,
                const float* a_d1, const float* a_d2,
                const float* imp_b2, const float* disc_b3,
                const float* cons_b3, const float* diff_b3, int B) {
    const int i = blockIdx.x * 256 + threadIdx.x;
    if (i >= B) return;
    const float ib = imp_b2[0], db = disc_b3[0], cb = cons_b3[0], fb = diff_b3[0];
    const float o6 = sigm(a_co[i] + cb);
    const float o7 = sigm(a_ce[i] + cb);
    const float o8 = sigm(a_imp1[i] + ib);
    const float o9 = sigm(a_imp1[B + i] + ib);
    out[6 * B + i] = o6;
    out[7 * B + i] = o7;
    out[8 * B + i] = o8;
    out[9 * B + i] = o9;
    out[10 * B + i] = sigm(a_imp2[i] + ib);
    out[11 * B + i] = sigm(a_imp2[B + i] + ib);
    out[12 * B + i] = sigm(a_d1[i] + db);
    out[14 * B + i] = sigm(a_d1[B + i] + db);
    out[13 * B + i] = sigm(a_d2[i] + db);
    out[15 * B + i] = sigm(a_d2[B + i] + db);
    out[16 * B + i] = sigm(a_df[i] + fb);
    const float v = out[0 * B + i] + out[1 * B + i] + out[4 * B + i] + out[5 * B + i] +
                    o7 + 0.5f * (o8 + o9);
    out[17 * B + i] = v * (1.f / 6.f);
}

extern "C" void kernel_launch(void* const* d_in, const int* in_sizes, int n_in,
                              void* d_out, int out_size, void* d_ws, size_t ws_size,
                              hipStream_t stream) {
    const int B = in_sizes[4];  // 16384
    const int B2 = 2 * B;
    float* out = (float*)d_out;
    const float* img  = (const float*)d_in[0];
    const float* txt  = (const float*)d_in[1];
    const float* eimg = (const float*)d_in[2];
    const float* etxt = (const float*)d_in[3];
    const float* info_w1 = (const float*)d_in[5];  const float* info_b1 = (const float*)d_in[6];
    const float* info_w2 = (const float*)d_in[7];  const float* info_b2 = (const float*)d_in[8];
    const float* imp_w1  = (const float*)d_in[9];  const float* imp_b1  = (const float*)d_in[10];
    const float* imp_w2  = (const float*)d_in[11]; const float* imp_b2  = (const float*)d_in[12];
    const float* disc_w1 = (const float*)d_in[13]; const float* disc_b1 = (const float*)d_in[14];
    const float* disc_w2 = (const float*)d_in[15]; const float* disc_b2 = (const float*)d_in[16];
    const float* disc_w3 = (const float*)d_in[17]; const float* disc_b3 = (const float*)d_in[18];
    const float* cons_w1 = (const float*)d_in[19]; const float* cons_b1 = (const float*)d_in[20];
    const float* cons_w2 = (const float*)d_in[21]; const float* cons_b2 = (const float*)d_in[22];
    const float* cons_w3 = (const float*)d_in[23]; const float* cons_b3 = (const float*)d_in[24];
    const float* diff_w1 = (const float*)d_in[25]; const float* diff_b1 = (const float*)d_in[26];
    const float* diff_w2 = (const float*)d_in[27]; const float* diff_b2 = (const float*)d_in[28];
    const float* diff_w3 = (const float*)d_in[29]; const float* diff_b3 = (const float*)d_in[30];

    char* wsp = (char*)d_ws;
    size_t off = 0;
    auto alloc = [&](size_t bytes) -> void* {
        void* p = wsp + off;
        off += (bytes + 255) & ~(size_t)255;
        return p;
    };
    // bf16 transposed weights [N][K]
    bfu* info1t = (bfu*)alloc((size_t)256 * 768 * 2);
    bfu* info2t = (bfu*)alloc((size_t)64 * 256 * 2);
    bfu* imp1t  = (bfu*)alloc((size_t)384 * 768 * 2);
    bfu* disc1t = (bfu*)alloc((size_t)256 * 768 * 2);
    bfu* disc2t = (bfu*)alloc((size_t)64 * 256 * 2);
    bfu* cons1t = (bfu*)alloc((size_t)768 * 1536 * 2);
    bfu* cons2t = (bfu*)alloc((size_t)384 * 768 * 2);
    bfu* diff1t = (bfu*)alloc((size_t)768 * 1536 * 2);
    bfu* diff2t = (bfu*)alloc((size_t)384 * 768 * 2);
    float* part = (float*)alloc((size_t)B2 * 4);
    // head accumulators: [imp1 2B][imp2 2B][cons_o B][cons_e B][diff B] zeroed,
    // then [disc1 2B][disc2 2B] direct-stored.
    float* accz = (float*)alloc((size_t)(7 * B + 4 * B) * 4);
    float* a_imp1 = accz;
    float* a_imp2 = accz + B2;
    float* a_co = accz + 2 * B2;
    float* a_ce = a_co + B;
    float* a_df = a_ce + B;
    float* a_d1 = a_df + B;
    float* a_d2 = a_d1 + B2;
    bfu* fA01 = (bfu*)alloc((size_t)B2 * 768 * 2);           // 50.3 MB
    bfu* X    = (bfu*)alloc((size_t)B2 * 768 * 2);           // 50.3 MB scratch
    bfu* Hi   = X;                                           // [2B x 256]
    bfu* Hd   = X + (size_t)B2 * 256;                        // [2B x 256]
    bfu* Hc_c = X;                                           // [B x 768] later
    bfu* Hc_d = X + (size_t)B * 768;                         // [B x 768] later
    (void)ws_size; (void)n_in; (void)out_size;  // ~111 MB total

    zero_k<<<dim3((7 * B + 255) / 256), 256, 0, stream>>>(accz, 7 * B);

    TPack tp;
    int blk = 0, ti = 0;
    auto setd = [&](const float* s, bfu* d, int K, int N) {
        tp.d[ti++] = {s, d, K, N, blk};
        blk += (K / 64) * (N / 64);
    };
    setd(info_w1, info1t, 768, 256);
    setd(info_w2, info2t, 256, 64);
    setd(imp_w1, imp1t, 768, 384);
    setd(disc_w1, disc1t, 768, 256);
    setd(disc_w2, disc2t, 256, 64);
    setd(cons_w1, cons1t, 1536, 768);
    setd(cons_w2, cons2t, 768, 384);
    setd(diff_w1, diff1t, 1536, 768);
    setd(diff_w2, diff2t, 768, 384);
    transpose_k<<<dim3(blk), 256, 0, stream>>>(tp);

    auto store_seg = [&](const bfu* A, const bfu* A2, const bfu* W, const float* b,
                         bfu* C, int ldc, int mode) -> Seg {
        return Seg{A, A2, W, b, nullptr, C, nullptr, ldc, mode};
    };
    auto dot_seg = [&](const bfu* A, const bfu* A2, const bfu* W, const float* b,
                       const float* dw, float* acc) -> Seg {
        return Seg{A, A2, W, b, dw, nullptr, acc, 0, 1};
    };
    const bfu* fB = fA01 + (size_t)B * 768;

    // ================= phase 1: image / text =================
    geomcast_k<<<dim3(B / 4, 2), 256, 0, stream>>>(img, txt, fA01, (bfu*)fB,
                                                   out + 0 * B, out + 1 * B, part, part + B);
    {   // fused info1 | imp1(+dot) | disc1 over shared A, N=896 (7 tiles)
        SegPack p;
        p.s[0] = store_seg(fA01, fA01, info1t, info_b1, Hi, 256, 2);
        p.s[1] = store_seg(fA01, fA01, info1t + (size_t)128 * 768, info_b1 + 128, Hi + 128, 256, 2);
        for (int i = 0; i < 3; ++i)
            p.s[2 + i] = dot_seg(fA01, fA01, imp1t + (size_t)128 * i * 768,
                                 imp_b1 + 128 * i, imp_w2 + 128 * i, a_imp1);
        p.s[5] = store_seg(fA01, fA01, disc1t, disc_b1, Hd, 256, 0);
        p.s[6] = store_seg(fA01, fA01, disc1t + (size_t)128 * 768, disc_b1 + 128, Hd + 128, 256, 0);
        for (int i = 7; i < 12; ++i) p.s[i] = p.s[0];
        gemm_k<<<dim3(7, B2 / 128), 256, 0, stream>>>(p, 768, 768, 768);
    }
    gemm64ent_k<<<dim3(B2 / 128), 256, 0, stream>>>(Hi, info2t, info_b2, part, out, B, 256, 256);
    gemm64dot_k<<<dim3(B2 / 128), 256, 0, stream>>>(Hd, disc2t, disc_b2, disc_w3, a_d1, 256, 256);
    {   // cons_o layer1: concat A, N=768 (6 store tiles) -> Hc_c
        SegPack p;
        for (int i = 0; i < 6; ++i)
            p.s[i] = store_seg(fA01, fB, cons1t + (size_t)128 * i * 1536,
                               cons_b1 + 128 * i, Hc_c + 128 * i, 768, 0);
        for (int i = 6; i < 12; ++i) p.s[i] = p.s[0];
        gemm_k<<<dim3(6, B / 128), 256, 0, stream>>>(p, 1536, 768, 768);
    }
    {   // cons_o layer2 + dot
        SegPack p;
        for (int i = 0; i < 3; ++i)
            p.s[i] = dot_seg(Hc_c, Hc_c, cons2t + (size_t)128 * i * 768,
                             cons_b2 + 128 * i, cons_w3 + 128 * i, a_co);
        for (int i = 3; i < 12; ++i) p.s[i] = p.s[0];
        gemm_k<<<dim3(3, B / 128), 256, 0, stream>>>(p, 768, 768, 768);
    }

    // ================= phase 2: enhanced image / text =================
    geomcast_k<<<dim3(B / 4, 2), 256, 0, stream>>>(eimg, etxt, fA01, (bfu*)fB,
                                                   out + 2 * B, out + 3 * B, nullptr, nullptr);
    {   // fused imp1(+dot) | disc1, N=640 (5 tiles)
        SegPack p;
        for (int i = 0; i < 3; ++i)
            p.s[i] = dot_seg(fA01, fA01, imp1t + (size_t)128 * i * 768,
                             imp_b1 + 128 * i, imp_w2 + 128 * i, a_imp2);
        p.s[3] = store_seg(fA01, fA01, disc1t, disc_b1, Hd, 256, 0);
        p.s[4] = store_seg(fA01, fA01, disc1t + (size_t)128 * 768, disc_b1 + 128, Hd + 128, 256, 0);
        for (int i = 5; i < 12; ++i) p.s[i] = p.s[0];
        gemm_k<<<dim3(5, B2 / 128), 256, 0, stream>>>(p, 768, 768, 768);
    }
    gemm64dot_k<<<dim3(B2 / 128), 256, 0, stream>>>(Hd, disc2t, disc_b2, disc_w3, a_d2, 256, 256);
    {   // cons_e + diff layer1 fused: shared concat A, N=1536 (12 tiles)
        SegPack p;
        for (int i = 0; i < 6; ++i) {
            p.s[i]     = store_seg(fA01, fB, cons1t + (size_t)128 * i * 1536,
                                   cons_b1 + 128 * i, Hc_c + 128 * i, 768, 0);
            p.s[6 + i] = store_seg(fA01, fB, diff1t + (size_t)128 * i * 1536,
                                   diff_b1 + 128 * i, Hc_d + 128 * i, 768, 0);
        }
        gemm_k<<<dim3(12, B / 128), 256, 0, stream>>>(p, 1536, 768, 768);
    }
    {   // cons_e l2+dot | diff l2+dot (per-seg A)
        SegPack p;
        for (int i = 0; i < 3; ++i) {
            p.s[i]     = dot_seg(Hc_c, Hc_c, cons2t + (size_t)128 * i * 768,
                                 cons_b2 + 128 * i, cons_w3 + 128 * i, a_ce);
            p.s[3 + i] = dot_seg(Hc_d, Hc_d, diff2t + (size_t)128 * i * 768,
                                 diff_b2 + 128 * i, diff_w3 + 128 * i, a_df);
        }
        for (int i = 6; i < 12; ++i) p.s[i] = p.s[0];
        gemm_k<<<dim3(6, B / 128), 256, 0, stream>>>(p, 768, 768, 768);
    }

    finalize_k<<<dim3((B + 255) / 256), 256, 0, stream>>>(out, a_imp1, a_imp2, a_co, a_ce,
                                                          a_df, a_d1, a_d2,
                                                          imp_b2, disc_b3, cons_b3, diff_b3, B);
}

// Round 5
// 724.329 us; speedup vs baseline: 1.3049x; 1.0085x over previous
//
#include <hip/hip_runtime.h>

typedef unsigned short bfu;                                     // bf16 storage
typedef __attribute__((ext_vector_type(8))) __bf16 bf16x8;      // MFMA A/B frag
typedef __attribute__((ext_vector_type(4))) float f32x4;        // MFMA C/D frag

__device__ __forceinline__ float bf2f(bfu u) {
    unsigned int x = ((unsigned int)u) << 16;
    return __builtin_bit_cast(float, x);
}
__device__ __forceinline__ bfu f2bf(float f) {  // round-nearest-even
    unsigned int u = __builtin_bit_cast(unsigned int, f);
    unsigned int r = (u + 0x7fffu + ((u >> 16) & 1u)) >> 16;
    return (bfu)r;
}
__device__ __forceinline__ float sigm(float x) { return 1.0f / (1.0f + __expf(-x)); }
// fast tanh-GELU (~1e-3 abs err) for sigmoid-smooth heads
__device__ __forceinline__ float gelu_f(float x) {
    const float y = 0.7978845608f * (x + 0.044715f * x * x * x);
    const float t = 1.f - 2.f / (__expf(2.f * y) + 1.f);
    return 0.5f * x * (1.f + t);
}
// exact erf GELU: info head only (round(sig*10) histogram is discontinuous)
__device__ __forceinline__ float gelu_x(float x) {
    return 0.5f * x * (1.0f + erff(x * 0.70710678118654752f));
}

// async global->LDS, 16B/lane; LDS dest = wave-uniform base + lane*16.
__device__ __forceinline__ void async16(const void* g, void* l) {
    __builtin_amdgcn_global_load_lds((const __attribute__((address_space(1))) void*)g,
                                     (__attribute__((address_space(3))) void*)l, 16, 0, 0);
}

// ---------------------------------------------------------------- transpose
struct TDesc { const float* src; bfu* dst; int K, N, blk0; };
struct TPack { TDesc d[9]; };

__global__ __launch_bounds__(256) void transpose_k(TPack p) {
    const int bid = blockIdx.x;
    int j = 0;
#pragma unroll
    for (int i = 1; i < 9; ++i)
        if (bid >= p.d[i].blk0) j = i;
    const TDesc d = p.d[j];
    const int local = bid - d.blk0;
    const int tkn = d.K >> 6;
    const int tk = local % tkn, tn = local / tkn;
    const int k0 = tk * 64, n0 = tn * 64;
    __shared__ float tile[64][65];
    const int tx = threadIdx.x & 63, ty = threadIdx.x >> 6;
#pragma unroll
    for (int i = 0; i < 16; ++i) {
        const int r = ty * 16 + i;
        tile[r][tx] = d.src[(size_t)(k0 + r) * d.N + n0 + tx];
    }
    __syncthreads();
#pragma unroll
    for (int i = 0; i < 16; ++i) {
        const int n = ty * 16 + i;
        d.dst[(size_t)(n0 + n) * d.K + k0 + tx] = f2bf(tile[tx][n]);
    }
}

// --------------------------- prep: zero accumulators + build padded disc-l2
__global__ __launch_bounds__(256)
void prep_k(float* accz, int nacc, bfu* disc2pad, const float* w3,
            const float* b2, float* w3pad, float* b2pad) {
    const int i = blockIdx.x * 256 + threadIdx.x;
    if (i < nacc) accz[i] = 0.f;
    if (i < 64 * 256) disc2pad[64 * 256 + i] = 0;     // zero pad rows 64..127
    if (i < 128) {
        w3pad[i] = (i < 64) ? w3[i] : 0.f;            // pad dot weights with 0
        b2pad[i] = (i < 64) ? b2[i] : 0.f;            // pad bias with 0
    }
}

// ------------------------------------------------------- geometric + cast
__global__ __launch_bounds__(256)
void geomcast_k(const float* F0, const float* F1, bfu* D0, bfu* D1,
                float* g0, float* g1, float* p0, float* p1) {
    const int z = blockIdx.y;
    const float* F = z ? F1 : F0;
    bfu* D = z ? D1 : D0;
    float* gout = z ? g1 : g0;
    float* part = z ? p1 : p0;
    const int wave = threadIdx.x >> 6, lane = threadIdx.x & 63;
    const int row = blockIdx.x * 4 + wave;
    const float* fr = F + (size_t)row * 768;
    bfu* dr = D + (size_t)row * 768;
    float sum = 0.f, ss = 0.f, cnt = 0.f;
#pragma unroll
    for (int i = 0; i < 3; ++i) {
        const float4 v = *(const float4*)(fr + i * 256 + lane * 4);
        sum += v.x + v.y + v.z + v.w;
        ss += v.x * v.x + v.y * v.y + v.z * v.z + v.w * v.w;
        cnt += ((fabsf(v.x) > 0.01f) ? 1.f : 0.f) + ((fabsf(v.y) > 0.01f) ? 1.f : 0.f) +
               ((fabsf(v.z) > 0.01f) ? 1.f : 0.f) + ((fabsf(v.w) > 0.01f) ? 1.f : 0.f);
        ushort4 b;
        b.x = f2bf(v.x); b.y = f2bf(v.y); b.z = f2bf(v.z); b.w = f2bf(v.w);
        *(ushort4*)(dr + i * 256 + lane * 4) = b;
    }
#pragma unroll
    for (int off = 32; off; off >>= 1) {
        sum += __shfl_xor(sum, off);
        ss  += __shfl_xor(ss, off);
        cnt += __shfl_xor(cnt, off);
    }
    if (lane == 0) {
        const float n = sqrtf(ss);
        const float nq = sigm((n - 1.f) * 2.f);
        const float sp = cnt * (1.f / 768.f);
        float var = (ss - sum * sum * (1.f / 768.f)) * (1.f / 767.f);
        var = fmaxf(var, 0.f);
        const float sq = sigm(sqrtf(var) * 10.f - 1.f);
        gout[row] = (nq + sp + sq) * (1.f / 3.f);
        if (part) {
            const float cq = (n > 0.01f) ? (1.f / 768.f) : 0.f;
            const float nc = fmaxf(n, 1e-12f);
            const float dq = sigm(ss / (nc * nc) - 0.5f);
            part[row] = (cq + dq) * (1.f / 3.f);
        }
    }
}

// ------------------------------------------------------------------- GEMM
// Per-seg descriptors now carry K/Ksplit/lda/Mtiles so heterogeneous GEMMs
// (different K, different M) batch into ONE launch (R4: thin 256-384-block
// dispatches were latency-bound). Staging uses per-lane rolling pointers
// (+=64/kt) instead of full per-kt address math (cuts staging VALU ~3x).
// XCD swizzle (id%8 = m%8) keeps A L2-resident per XCD (R3-proven).
struct Seg {
    const bfu* A; const bfu* A2;    // A2 supplies cols >= Ksplit (concat)
    const bfu* W;                    // this tile's W rows [128][K]
    const float* bias;               // per-col bias (tile-local, 128)
    const float* dotw;               // mode1: dot weights (tile-local, 128)
    bfu* C;                          // mode0/2: store base (tile-local cols)
    float* acc;                      // mode1: per-row fp32 accumulator
    int ldc, mode, K, Ksplit, lda, Mtiles;
};
struct SegPack { Seg s[13]; };

__global__ __launch_bounds__(256)
void gemm_k(SegPack p) {
    constexpr int BK = 64, MT = 4, NT = 4;
    __shared__ bfu As[128 * BK];
    __shared__ bfu Ws[128 * BK];
    const int NTt = gridDim.x;
    const int g = blockIdx.y * NTt + blockIdx.x;
    const int G8 = NTt * 8;                       // gridDim.y % 8 == 0 always
    const int m = (g / G8) * 8 + (g & 7);
    const int n = (g % G8) >> 3;
    const Seg sg = p.s[n];
    if (m >= sg.Mtiles) return;                   // uniform early-exit
    const int t = threadIdx.x;
    const int wave = t >> 6, lane = t & 63;
    const int row_l = lane & 15, kq = lane >> 4;
    const int m0 = m * 128;
    const int wm = wave >> 1, wn = wave & 1;
    const int wrow0 = wm * 64, wcol0 = wn * 64;

    // rolling per-lane staging pointers (XOR-swizzled source chunk; r&7 is
    // i-independent since rows step by 32)
    const int r0 = t >> 3;
    const int cc = ((t & 7) ^ (r0 & 7)) << 3;
    const size_t strA = (size_t)32 * sg.lda;
    const size_t strW = (size_t)32 * sg.K;
    const bfu* pA[4];
    const bfu* pW[4];
#pragma unroll
    for (int i = 0; i < 4; ++i) {
        pA[i] = sg.A + (size_t)(m0 + r0) * sg.lda + cc + i * strA;
        pW[i] = sg.W + (size_t)r0 * sg.K + cc + i * strW;
    }
    const int nkt = sg.K >> 6;
    const int ktsw = (sg.Ksplit < sg.K) ? (sg.Ksplit >> 6) : 0x7fffffff;

    f32x4 acc[MT][NT] = {};

    for (int kt = 0; kt < nkt; ++kt) {
        if (kt == ktsw) {                         // concat boundary: switch A
#pragma unroll
            for (int i = 0; i < 4; ++i)
                pA[i] = sg.A2 + (size_t)(m0 + r0) * sg.lda + cc + i * strA;
        }
#pragma unroll
        for (int i = 0; i < 4; ++i)
            async16(pA[i], As + ((i * 256 + wave * 64) << 3));
#pragma unroll
        for (int i = 0; i < 4; ++i)
            async16(pW[i], Ws + ((i * 256 + wave * 64) << 3));
        __syncthreads();
#pragma unroll
        for (int ks = 0; ks < 2; ++ks) {
            bf16x8 af[MT], bfr[NT];
#pragma unroll
            for (int mi = 0; mi < MT; ++mi) {
                const int rA = wrow0 + mi * 16 + row_l;
                af[mi] = *(const bf16x8*)(As + rA * BK + (((ks * 4 + kq) ^ (rA & 7)) << 3));
            }
#pragma unroll
            for (int ni = 0; ni < NT; ++ni) {
                const int rB = wcol0 + ni * 16 + row_l;
                bfr[ni] = *(const bf16x8*)(Ws + rB * BK + (((ks * 4 + kq) ^ (rB & 7)) << 3));
            }
#pragma unroll
            for (int mi = 0; mi < MT; ++mi)
#pragma unroll
                for (int ni = 0; ni < NT; ++ni)
                    acc[mi][ni] = __builtin_amdgcn_mfma_f32_16x16x32_bf16(af[mi], bfr[ni], acc[mi][ni], 0, 0, 0);
        }
        __syncthreads();
#pragma unroll
        for (int i = 0; i < 4; ++i) { pA[i] += BK; pW[i] += BK; }
    }

    // C/D layout: col=lane&15, row=quad*4+reg (m89/m91-verified)
    if (sg.mode == 0) {
#pragma unroll
        for (int ni = 0; ni < NT; ++ni) {
            const int col = wcol0 + ni * 16 + row_l;
            const float bv = sg.bias[col];
#pragma unroll
            for (int mi = 0; mi < MT; ++mi)
#pragma unroll
                for (int r = 0; r < 4; ++r) {
                    const int row = m0 + wrow0 + mi * 16 + kq * 4 + r;
                    sg.C[(size_t)row * sg.ldc + col] = f2bf(gelu_f(acc[mi][ni][r] + bv));
                }
        }
    } else if (sg.mode == 2) {
#pragma unroll
        for (int ni = 0; ni < NT; ++ni) {
            const int col = wcol0 + ni * 16 + row_l;
            const float bv = sg.bias[col];
#pragma unroll
            for (int mi = 0; mi < MT; ++mi)
#pragma unroll
                for (int r = 0; r < 4; ++r) {
                    const int row = m0 + wrow0 + mi * 16 + kq * 4 + r;
                    sg.C[(size_t)row * sg.ldc + col] = f2bf(gelu_x(acc[mi][ni][r] + bv));
                }
        }
    } else {
#pragma unroll
        for (int mi = 0; mi < MT; ++mi)
#pragma unroll
            for (int r = 0; r < 4; ++r) {
                float s = 0.f;
#pragma unroll
                for (int ni = 0; ni < NT; ++ni) {
                    const int col = wcol0 + ni * 16 + row_l;
                    s += sg.dotw[col] * gelu_f(acc[mi][ni][r] + sg.bias[col]);
                }
                s += __shfl_xor(s, 1); s += __shfl_xor(s, 2);
                s += __shfl_xor(s, 4); s += __shfl_xor(s, 8);
                if (row_l == 0)
                    atomicAdd(sg.acc + m0 + wrow0 + mi * 16 + kq * 4 + r, s);
            }
    }
}

// -------------------------------- BN=64 GEMM + fused entropy (info l2)
__global__ __launch_bounds__(256)
void gemm64ent_k(const bfu* __restrict__ A, const bfu* __restrict__ W,
                 const float* __restrict__ bias, const float* __restrict__ part,
                 float* out, int B, int K, int lda) {
    constexpr int BK = 64, MT = 2, NT = 4;
    __shared__ __align__(16) float smemf[8320];   // 33280 B: staging | ET union
    bfu* As = (bfu*)smemf;                        // 128x64 bf16 = 16 KB
    bfu* Ws = (bfu*)smemf + 128 * BK;             // 64x64 bf16 = 8 KB
    float* ET = smemf;                            // 128 x 65 fp32 after K-loop
    const int t = threadIdx.x;
    const int wave = t >> 6, lane = t & 63;
    const int row_l = lane & 15, kq = lane >> 4;
    const int m0 = blockIdx.x * 128;
    const int wrow0 = wave * 32;
    f32x4 acc[MT][NT] = {};
    const int nkt = K / BK;
    for (int kt = 0; kt < nkt; ++kt) {
        const int k0 = kt * BK;
#pragma unroll
        for (int i = 0; i < 4; ++i) {
            const int c = i * 256 + t;
            const int r = c >> 3, s = c & 7;
            const int cc = (s ^ (r & 7)) << 3;
            async16(A + (size_t)(m0 + r) * lda + k0 + cc, As + ((i * 256 + wave * 64) << 3));
        }
#pragma unroll
        for (int i = 0; i < 2; ++i) {
            const int c = i * 256 + t;
            const int r = c >> 3, s = c & 7;
            const int cc = (s ^ (r & 7)) << 3;
            async16(W + (size_t)r * K + k0 + cc, Ws + ((i * 256 + wave * 64) << 3));
        }
        __syncthreads();
#pragma unroll
        for (int ks = 0; ks < 2; ++ks) {
            bf16x8 af[MT], bfr[NT];
#pragma unroll
            for (int mi = 0; mi < MT; ++mi) {
                const int rA = wrow0 + mi * 16 + row_l;
                af[mi] = *(const bf16x8*)(As + rA * BK + (((ks * 4 + kq) ^ (rA & 7)) << 3));
            }
#pragma unroll
            for (int ni = 0; ni < NT; ++ni) {
                const int rB = ni * 16 + row_l;
                bfr[ni] = *(const bf16x8*)(Ws + rB * BK + (((ks * 4 + kq) ^ (rB & 7)) << 3));
            }
#pragma unroll
            for (int mi = 0; mi < MT; ++mi)
#pragma unroll
                for (int ni = 0; ni < NT; ++ni)
                    acc[mi][ni] = __builtin_amdgcn_mfma_f32_16x16x32_bf16(af[mi], bfr[ni], acc[mi][ni], 0, 0, 0);
        }
        __syncthreads();
    }
    // dump 128x64 fp32 logits (no activation) to LDS
#pragma unroll
    for (int mi = 0; mi < MT; ++mi)
#pragma unroll
        for (int ni = 0; ni < NT; ++ni) {
            const int col = ni * 16 + row_l;
            const float bv = bias[col];
#pragma unroll
            for (int r = 0; r < 4; ++r)
                ET[(wrow0 + mi * 16 + kq * 4 + r) * 65 + col] = acc[mi][ni][r] + bv;
        }
    __syncthreads();
    if (t < 128) {   // one thread per row: histogram entropy over 64 logits
        int cnt[11];
#pragma unroll
        for (int b = 0; b < 11; ++b) cnt[b] = 0;
        for (int j = 0; j < 64; ++j) {
            const int d = (int)rintf(sigm(ET[t * 65 + j]) * 10.f);
#pragma unroll
            for (int b = 0; b < 11; ++b) cnt[b] += (d == b);
        }
        float ent = 0.f;
#pragma unroll
        for (int b = 0; b < 11; ++b) {
            if (cnt[b] > 0) {
                const float pp = (float)cnt[b] * (1.f / 64.f);
                ent -= pp * __logf(pp + 1e-8f);
            }
        }
        const int row = m0 + t;
        const int orow = (row < B) ? 4 : 5;
        const int rl = (row < B) ? row : row - B;
        out[(size_t)orow * B + rl] = part[row] + sigm(ent - 2.f) * (1.f / 3.f);
    }
}

// --------------- finalize: sigmoids over fused-dot accumulators + overall
__global__ __launch_bounds__(256)
void finalize_k(float* out, const float* a_imp1, const float* a_imp2,
                const float* a_co, const float* a_ce, const float* a_df,
                const float* a_d1, const float* a_d2,
                const float* imp_b2, const float* disc_b3,
                const float* cons_b3, const float* diff_b3, int B) {
    const int i = blockIdx.x * 256 + threadIdx.x;
    if (i >= B) return;
    const float ib = imp_b2[0], db = disc_b3[0], cb = cons_b3[0], fb = diff_b3[0];
    const float o6 = sigm(a_co[i] + cb);
    const float o7 = sigm(a_ce[i] + cb);
    const float o8 = sigm(a_imp1[i] + ib);
    const float o9 = sigm(a_imp1[B + i] + ib);
    out[6 * B + i] = o6;
    out[7 * B + i] = o7;
    out[8 * B + i] = o8;
    out[9 * B + i] = o9;
    out[10 * B + i] = sigm(a_imp2[i] + ib);
    out[11 * B + i] = sigm(a_imp2[B + i] + ib);
    out[12 * B + i] = sigm(a_d1[i] + db);
    out[14 * B + i] = sigm(a_d1[B + i] + db);
    out[13 * B + i] = sigm(a_d2[i] + db);
    out[15 * B + i] = sigm(a_d2[B + i] + db);
    out[16 * B + i] = sigm(a_df[i] + fb);
    const float v = out[0 * B + i] + out[1 * B + i] + out[4 * B + i] + out[5 * B + i] +
                    o7 + 0.5f * (o8 + o9);
    out[17 * B + i] = v * (1.f / 6.f);
}

extern "C" void kernel_launch(void* const* d_in, const int* in_sizes, int n_in,
                              void* d_out, int out_size, void* d_ws, size_t ws_size,
                              hipStream_t stream) {
    const int B = in_sizes[4];  // 16384
    const int B2 = 2 * B;
    float* out = (float*)d_out;
    const float* img  = (const float*)d_in[0];
    const float* txt  = (const float*)d_in[1];
    const float* eimg = (const float*)d_in[2];
    const float* etxt = (const float*)d_in[3];
    const float* info_w1 = (const float*)d_in[5];  const float* info_b1 = (const float*)d_in[6];
    const float* info_w2 = (const float*)d_in[7];  const float* info_b2 = (const float*)d_in[8];
    const float* imp_w1  = (const float*)d_in[9];  const float* imp_b1  = (const float*)d_in[10];
    const float* imp_w2  = (const float*)d_in[11]; const float* imp_b2  = (const float*)d_in[12];
    const float* disc_w1 = (const float*)d_in[13]; const float* disc_b1 = (const float*)d_in[14];
    const float* disc_w2 = (const float*)d_in[15]; const float* disc_b2 = (const float*)d_in[16];
    const float* disc_w3 = (const float*)d_in[17]; const float* disc_b3 = (const float*)d_in[18];
    const float* cons_w1 = (const float*)d_in[19]; const float* cons_b1 = (const float*)d_in[20];
    const float* cons_w2 = (const float*)d_in[21]; const float* cons_b2 = (const float*)d_in[22];
    const float* cons_w3 = (const float*)d_in[23]; const float* cons_b3 = (const float*)d_in[24];
    const float* diff_w1 = (const float*)d_in[25]; const float* diff_b1 = (const float*)d_in[26];
    const float* diff_w2 = (const float*)d_in[27]; const float* diff_b2 = (const float*)d_in[28];
    const float* diff_w3 = (const float*)d_in[29]; const float* diff_b3 = (const float*)d_in[30];

    char* wsp = (char*)d_ws;
    size_t off = 0;
    auto alloc = [&](size_t bytes) -> void* {
        void* p = wsp + off;
        off += (bytes + 255) & ~(size_t)255;
        return p;
    };
    // bf16 transposed weights [N][K]; disc2 padded to 128 N-rows
    bfu* info1t = (bfu*)alloc((size_t)256 * 768 * 2);
    bfu* info2t = (bfu*)alloc((size_t)64 * 256 * 2);
    bfu* imp1t  = (bfu*)alloc((size_t)384 * 768 * 2);
    bfu* disc1t = (bfu*)alloc((size_t)256 * 768 * 2);
    bfu* disc2p = (bfu*)alloc((size_t)128 * 256 * 2);   // rows 64-127 zeroed
    bfu* cons1t = (bfu*)alloc((size_t)768 * 1536 * 2);
    bfu* cons2t = (bfu*)alloc((size_t)384 * 768 * 2);
    bfu* diff1t = (bfu*)alloc((size_t)768 * 1536 * 2);
    bfu* diff2t = (bfu*)alloc((size_t)384 * 768 * 2);
    float* w3pad = (float*)alloc(128 * 4);
    float* b2pad = (float*)alloc(128 * 4);
    float* part = (float*)alloc((size_t)B2 * 4);
    // zeroed accumulators: imp1 2B | imp2 2B | co B | ce B | df B | d1 2B | d2 2B
    float* accz = (float*)alloc((size_t)11 * B * 4);
    float* a_imp1 = accz;
    float* a_imp2 = accz + B2;
    float* a_co = accz + 2 * B2;
    float* a_ce = a_co + B;
    float* a_df = a_ce + B;
    float* a_d1 = a_df + B;
    float* a_d2 = a_d1 + B2;
    bfu* fA01 = (bfu*)alloc((size_t)B2 * 768 * 2);      // 50.3 MB features
    bfu* X    = (bfu*)alloc((size_t)B * 2048 * 2);      // 67.1 MB hidden
    bfu* Hd   = X;                                      // [2B x 256]
    bfu* Hi   = X + (size_t)B * 512;                    // [2B x 256] (ph1 only)
    bfu* Hc_c = X + (size_t)B * 512;                    // [B x 768] after ent
    bfu* Hc_d = X + (size_t)B * 1280;                   // [B x 768]
    (void)ws_size; (void)n_in; (void)out_size;          // ~126 MB total

    prep_k<<<dim3((11 * B + 255) / 256), 256, 0, stream>>>(accz, 11 * B, disc2p,
                                                           disc_w3, disc_b2, w3pad, b2pad);
    TPack tp;
    int blk = 0, ti = 0;
    auto setd = [&](const float* s, bfu* d, int K, int N) {
        tp.d[ti++] = {s, d, K, N, blk};
        blk += (K / 64) * (N / 64);
    };
    setd(info_w1, info1t, 768, 256);
    setd(info_w2, info2t, 256, 64);
    setd(imp_w1, imp1t, 768, 384);
    setd(disc_w1, disc1t, 768, 256);
    setd(disc_w2, disc2p, 256, 64);                     // rows 0-63 of padded
    setd(cons_w1, cons1t, 1536, 768);
    setd(cons_w2, cons2t, 768, 384);
    setd(diff_w1, diff1t, 1536, 768);
    setd(diff_w2, diff2t, 768, 384);
    transpose_k<<<dim3(blk), 256, 0, stream>>>(tp);

    auto st_seg = [&](const bfu* A, const bfu* A2, const bfu* W, const float* b,
                      bfu* C, int ldc, int mode, int K, int Ksplit, int lda, int Mt) -> Seg {
        return Seg{A, A2, W, b, nullptr, C, nullptr, ldc, mode, K, Ksplit, lda, Mt};
    };
    auto dt_seg = [&](const bfu* A, const bfu* W, const float* b, const float* dw,
                      float* acc, int K, int lda, int Mt) -> Seg {
        return Seg{A, nullptr, W, b, dw, nullptr, acc, 0, 1, K, K, lda, Mt};
    };
    const bfu* fB = fA01 + (size_t)B * 768;
    const int MT2 = B2 / 128, MT1 = B / 128;   // 256 / 128 m-tiles

    // ================= phase 1: image / text =================
    geomcast_k<<<dim3(B / 4, 2), 256, 0, stream>>>(img, txt, fA01, (bfu*)fB,
                                                   out + 0 * B, out + 1 * B, part, part + B);
    {   // BIG1: info1(erf)x2 | imp1-dot x3 | disc1 x2, K=768, M=2B
        SegPack p;
        p.s[0] = st_seg(fA01, nullptr, info1t, info_b1, Hi, 256, 2, 768, 768, 768, MT2);
        p.s[1] = st_seg(fA01, nullptr, info1t + (size_t)128 * 768, info_b1 + 128, Hi + 128, 256, 2, 768, 768, 768, MT2);
        for (int i = 0; i < 3; ++i)
            p.s[2 + i] = dt_seg(fA01, imp1t + (size_t)128 * i * 768, imp_b1 + 128 * i,
                                imp_w2 + 128 * i, a_imp1, 768, 768, MT2);
        p.s[5] = st_seg(fA01, nullptr, disc1t, disc_b1, Hd, 256, 0, 768, 768, 768, MT2);
        p.s[6] = st_seg(fA01, nullptr, disc1t + (size_t)128 * 768, disc_b1 + 128, Hd + 128, 256, 0, 768, 768, 768, MT2);
        gemm_k<<<dim3(7, MT2), 256, 0, stream>>>(p);
    }
    gemm64ent_k<<<dim3(MT2), 256, 0, stream>>>(Hi, info2t, info_b2, part, out, B, 256, 256);
    {   // BIG2: disc2-dot (K=256, padded 128) | cons1 x6 (K=1536 concat)
        SegPack p;
        p.s[0] = dt_seg(Hd, disc2p, b2pad, w3pad, a_d1, 256, 256, MT2);
        for (int i = 0; i < 6; ++i)
            p.s[1 + i] = st_seg(fA01, fB, cons1t + (size_t)128 * i * 1536,
                                cons_b1 + 128 * i, Hc_c + 128 * i, 768, 0, 1536, 768, 768, MT1);
        gemm_k<<<dim3(7, MT2), 256, 0, stream>>>(p);
    }

    // ================= phase 2: enhanced image / text =================
    geomcast_k<<<dim3(B / 4, 2), 256, 0, stream>>>(eimg, etxt, fA01, (bfu*)fB,
                                                   out + 2 * B, out + 3 * B, nullptr, nullptr);
    {   // BIG3: imp1-dot x3 | disc1 x2 (ph2 A) | cons2-dot x3 (ph1 Hc_c)
        SegPack p;
        for (int i = 0; i < 3; ++i)
            p.s[i] = dt_seg(fA01, imp1t + (size_t)128 * i * 768, imp_b1 + 128 * i,
                            imp_w2 + 128 * i, a_imp2, 768, 768, MT2);
        p.s[3] = st_seg(fA01, nullptr, disc1t, disc_b1, Hd, 256, 0, 768, 768, 768, MT2);
        p.s[4] = st_seg(fA01, nullptr, disc1t + (size_t)128 * 768, disc_b1 + 128, Hd + 128, 256, 0, 768, 768, 768, MT2);
        for (int i = 0; i < 3; ++i)
            p.s[5 + i] = dt_seg(Hc_c, cons2t + (size_t)128 * i * 768, cons_b2 + 128 * i,
                                cons_w3 + 128 * i, a_co, 768, 768, MT1);
        gemm_k<<<dim3(8, MT2), 256, 0, stream>>>(p);
    }
    {   // BIG4: disc2-dot (ph2) | cons1 x6 | diff1 x6 (shared concat A)
        SegPack p;
        p.s[0] = dt_seg(Hd, disc2p, b2pad, w3pad, a_d2, 256, 256, MT2);
        for (int i = 0; i < 6; ++i) {
            p.s[1 + i] = st_seg(fA01, fB, cons1t + (size_t)128 * i * 1536,
                                cons_b1 + 128 * i, Hc_c + 128 * i, 768, 0, 1536, 768, 768, MT1);
            p.s[7 + i] = st_seg(fA01, fB, diff1t + (size_t)128 * i * 1536,
                                diff_b1 + 128 * i, Hc_d + 128 * i, 768, 0, 1536, 768, 768, MT1);
        }
        gemm_k<<<dim3(13, MT2), 256, 0, stream>>>(p);
    }
    {   // BIG5: cons2-dot x3 | diff2-dot x3
        SegPack p;
        for (int i = 0; i < 3; ++i) {
            p.s[i]     = dt_seg(Hc_c, cons2t + (size_t)128 * i * 768, cons_b2 + 128 * i,
                                cons_w3 + 128 * i, a_ce, 768, 768, MT1);
            p.s[3 + i] = dt_seg(Hc_d, diff2t + (size_t)128 * i * 768, diff_b2 + 128 * i,
                                diff_w3 + 128 * i, a_df, 768, 768, MT1);
        }
        gemm_k<<<dim3(6, MT1), 256, 0, stream>>>(p);
    }

    finalize_k<<<dim3((B + 255) / 256), 256, 0, stream>>>(out, a_imp1, a_imp2, a_co, a_ce,
                                                          a_df, a_d1, a_d2,
                                                          imp_b2, disc_b3, cons_b3, diff_b3, B);
}